// Round 12
// baseline (3540.827 us; speedup 1.0000x reference)
//
#include <hip/hip_runtime.h>
#include <hip/hip_bf16.h>
#include <hip/hip_fp16.h>

#define DI     2048
#define LSEQ   2048
#define NBATCH 2
#define MROWS  4096        // NBATCH * LSEQ
#define EPSF   1e-5f
#define NSTEPS 31
#define NCH    64          // scan chunks per sequence
#define CL     32          // chunk length (NCH*CL == LSEQ)

typedef float    f32x4 __attribute__((ext_vector_type(4)));
typedef float    f32x2 __attribute__((ext_vector_type(2)));
typedef _Float16 f16x8 __attribute__((ext_vector_type(8)));
typedef _Float16 f16x2 __attribute__((ext_vector_type(2)));
using f16 = _Float16;

// ------------------------- static device arena -------------------------
constexpr size_t MB = 1024ull * 1024ull;
constexpr size_t OFF_APARAM =   0 * MB;   // f16 [4096][4096] = [x_i | h_sh]   (32 MB)
constexpr size_t OFF_WVT    =  32 * MB;   // f16 [2048][4096] W_v^T            (16 MB)
constexpr size_t OFF_WCT    =  48 * MB;   // f16 [2048][4096] W_c^T            (16 MB)
constexpr size_t OFF_WBT    =  64 * MB;   // f16 [2048][2048] W_b^T            ( 8 MB)  (contiguous
constexpr size_t OFF_WLT    =  72 * MB;   // f16 [2048][2048] W_lam^T          ( 8 MB)   with WBT)
constexpr size_t OFF_WINT   =  80 * MB;   // f16 [4096][1024] W_in^T           ( 8 MB)
constexpr size_t OFF_WOT    =  88 * MB;   // f16 [1024][2048] W_out^T          ( 4 MB)
constexpr size_t OFF_AX     =  92 * MB;   // f16 [4096][1024] x                ( 8 MB)
constexpr size_t OFF_Z      = 100 * MB;   // f16 [4096][2048] z                (16 MB)
constexpr size_t OFF_U      = 116 * MB;   // f16 [4096][2048] u (normed)       (16 MB)
constexpr size_t OFF_XI     = 132 * MB;   // f32 [4096][2048] x_i              (32 MB)
constexpr size_t OFF_BXH    = 164 * MB;   // f16 b*x_i        (step-invariant) (16 MB)
constexpr size_t OFF_LAMH   = 180 * MB;   // f16 lam          (step-invariant) (16 MB)
constexpr size_t OFF_H      = 196 * MB;   // f32 h (step-varying: stays f32)   (32 MB)
constexpr size_t OFF_VRAW   = 228 * MB;   // f32 v_raw / u_raw                 (32 MB)
constexpr size_t OFF_VX     = 260 * MB;   // f32 x_i@Wv_top + b_v              (32 MB)
constexpr size_t OFF_SSP    = 292 * MB;   // f32 [4096][64] ss partials        ( 1 MB)
constexpr size_t OFF_DRP    = 293 * MB;   // f32 [4096][64] dr partials        ( 1 MB)
constexpr size_t OFF_CA     = 294 * MB;   // f32 [2][64][2048]                 ( 1 MB)
constexpr size_t OFF_CB     = 295 * MB;   //                                   ( 1 MB)
constexpr size_t ARENA_SZ   = 296 * MB;

__device__ __align__(256) char g_buf[ARENA_SZ];

// ------------------------- helpers -------------------------
__device__ __forceinline__ void gload16(const void* g, void* l) {
  __builtin_amdgcn_global_load_lds((const __attribute__((address_space(1))) void*)g,
                                   (__attribute__((address_space(3))) void*)l, 16, 0, 0);
}
__device__ __forceinline__ float siluf(float x) { return x / (1.0f + __expf(-x)); }
__device__ __forceinline__ float sigmf(float x) { return 1.0f / (1.0f + __expf(-x)); }

// ------------------------- GEMM: C = A(f16,MxK) * Bt(f16,NxK)^T -------------------------
// 128x128 tile, BK=32 (32 KB LDS dbuf -> 4 blocks/CU, 100% occupancy), 8 waves,
// 64x32 per wave, counted vmcnt(2), XCD swizzle.  Accumulation order identical to the
// BK=64 round-11 kernel (k=0..31,32..63,...) -> bit-identical outputs.
// Swizzle (64B rows): 16B slot s of row r holds source slot s ^ ((r>>1)&3); bank-quad
// q=(4r+slot) mod 8 hits each quad exactly 2x over any 16-row group = free 2-way.
// EPI 0: outf[row*N+col] = acc
// EPI 1: split xz: col<DI -> xi(f32)+Aparam(f16); else z(f16)
// EPI 4: v = silu(acc + aux2(vx)); outf(vraw)=v; ss/dr partials (auxb=bxh f16, aux0=h f32)
// EPI 5: outf(uraw) = silu(acc) * aux0(h) * silu(auxb(z))
// EPI 6: outf(vx) = acc + aux1[col](b_v)
// EPI 8: fused pair (N=4096): col<DI -> bxh = f16(silu(acc)*aux0(xi));
//        else lamh = f16(sigm(acc + aux1[col-DI](b_lam)))
template<int EPI>
__global__ __launch_bounds__(512, 8) void gemm_f16(
    const f16* __restrict__ A, int lda,
    const f16* __restrict__ Bt, int ldb,
    int N, int K,
    float* __restrict__ outf,
    f16* __restrict__ outb,
    f16* __restrict__ outb2,
    const float* __restrict__ aux0,
    const float* __restrict__ aux1,
    const float* __restrict__ aux2,
    const f16* __restrict__ auxb,
    float* __restrict__ ssp,
    float* __restrict__ drp)
{
  __shared__ char As[2][128 * 32 * 2];   // 8 KB per buffer
  __shared__ char Bs[2][128 * 32 * 2];

  const int tid = threadIdx.x;
  const int l   = tid & 63;
  const int w   = tid >> 6;              // 0..7
  const int wm  = (w >> 2) << 6;         // 0 or 64   (64-row wave tile)
  const int wn  = (w & 3) << 5;          // 0/32/64/96 (32-col wave tile)
  const int ntn = N >> 7;
  // XCD-aware swizzle (grid % 8 == 0 for all our shapes)
  const int nwg = (int)gridDim.x;
  const int id  = (blockIdx.x & 7) * (nwg >> 3) + (blockIdx.x >> 3);
  const int bm  = id / ntn;
  const int bn  = id % ntn;
  const size_t m0 = (size_t)bm << 7;
  const size_t n0 = (size_t)bn << 7;

  const char* Ab = (const char*)A + m0 * (size_t)(lda * 2);
  const char* Bb = (const char*)Bt + n0 * (size_t)(ldb * 2);

  f32x4 acc[4][2];
#pragma unroll
  for (int i = 0; i < 4; ++i)
#pragma unroll
    for (int j = 0; j < 2; ++j) acc[i][j] = (f32x4){0.f, 0.f, 0.f, 0.f};

  auto stage = [&](int bf, int kte) {   // kte = element offset in K; 2 loads/thread
    const int o   = tid;                   // 16B-chunk 0..511
    const int r   = o >> 2;                // tile row 0..127
    const int cb  = (o & 3) << 4;          // byte col within 64B row
    const int scb = cb ^ (((r >> 1) & 3) << 4);   // pre-swizzled source col
    gload16(Ab + (size_t)r * (size_t)(lda * 2) + (size_t)kte * 2 + scb, &As[bf][o << 4]);
    gload16(Bb + (size_t)r * (size_t)(ldb * 2) + (size_t)kte * 2 + scb, &Bs[bf][o << 4]);
  };

  const int nt = K >> 5;
  stage(0, 0);                               // prologue: tile 0 in flight (2 loads/thread)
  for (int t = 0; t < nt; ++t) {
    const int cur = t & 1;
    if (t + 1 < nt) {
      stage(cur ^ 1, (t + 1) << 5);          // prefetch next tile (2 more in flight)
      asm volatile("s_waitcnt vmcnt(2)" ::: "memory");   // wait only for tile t
    } else {
      asm volatile("s_waitcnt vmcnt(0)" ::: "memory");
    }
    __builtin_amdgcn_s_barrier();
    __builtin_amdgcn_sched_barrier(0);
    const char* Asc = As[cur];
    const char* Bsc = Bs[cur];
    {
      f16x8 af[4], bfr[2];
      const int kb = (l >> 4) << 4;          // 16B slot of this lane's K-slice
#pragma unroll
      for (int i = 0; i < 4; ++i) {
        const int Ra = wm + (i << 4) + (l & 15);
        af[i] = *(const f16x8*)(Asc + (Ra << 6) + (kb ^ (((Ra >> 1) & 3) << 4)));
      }
#pragma unroll
      for (int j = 0; j < 2; ++j) {
        const int Rb = wn + (j << 4) + (l & 15);
        bfr[j] = *(const f16x8*)(Bsc + (Rb << 6) + (kb ^ (((Rb >> 1) & 3) << 4)));
      }
#pragma unroll
      for (int i = 0; i < 4; ++i)
#pragma unroll
        for (int j = 0; j < 2; ++j)
          acc[i][j] = __builtin_amdgcn_mfma_f32_16x16x32_f16(af[i], bfr[j], acc[i][j], 0, 0, 0);
    }
    __builtin_amdgcn_sched_barrier(0);
    __builtin_amdgcn_s_barrier();
    __builtin_amdgcn_sched_barrier(0);
  }

  // epilogue: C/D layout col=lane&15, row=(lane>>4)*4+reg
  if constexpr (EPI == 4) {
#pragma unroll
    for (int i = 0; i < 4; ++i) {
#pragma unroll
      for (int rg = 0; rg < 4; ++rg) {
        const size_t row = m0 + wm + (i << 4) + ((l >> 4) << 2) + rg;
        float ssl = 0.f, drl = 0.f;
#pragma unroll
        for (int j = 0; j < 2; ++j) {
          const size_t col = n0 + wn + (j << 4) + (l & 15);
          const size_t idx = (row << 11) + col;
          const float v = siluf(acc[i][j][rg] + aux2[idx]);
          outf[idx] = v;
          ssl += v * v;
          drl += ((float)auxb[idx] - aux0[idx]) * v;   // (bx - h_prev) * v
        }
#pragma unroll
        for (int m = 8; m; m >>= 1) {           // reduce within 16-lane col group
          ssl += __shfl_xor(ssl, m);
          drl += __shfl_xor(drl, m);
        }
        if ((l & 15) == 0) {
          const int nb = (int)((n0 + wn) >> 5);  // 0..63 (32-col slots)
          ssp[(row << 6) + nb] = ssl;
          drp[(row << 6) + nb] = drl;
        }
      }
    }
  } else {
#pragma unroll
    for (int i = 0; i < 4; ++i) {
#pragma unroll
      for (int j = 0; j < 2; ++j) {
#pragma unroll
        for (int rg = 0; rg < 4; ++rg) {
          const size_t row = m0 + wm + (i << 4) + ((l >> 4) << 2) + rg;
          const size_t col = n0 + wn + (j << 4) + (l & 15);
          const float v = acc[i][j][rg];
          if constexpr (EPI == 0) {
            outf[row * (size_t)N + col] = v;
          } else if constexpr (EPI == 1) {
            if (col < DI) {
              outf[(row << 11) + col] = v;
              outb[(row << 12) + col] = (f16)v;
            } else {
              outb2[(row << 11) + (col - DI)] = (f16)v;
            }
          } else if constexpr (EPI == 5) {
            const size_t idx = (row << 11) + col;
            outf[idx] = siluf(v) * aux0[idx] * siluf((float)auxb[idx]);
          } else if constexpr (EPI == 6) {
            const size_t idx = (row << 11) + col;
            outf[idx] = v + aux1[col];
          } else if constexpr (EPI == 8) {
            if (col < DI) {
              const size_t idx = (row << 11) + col;
              outb[idx] = (f16)(siluf(v) * aux0[idx]);          // bxh
            } else {
              const size_t idx = (row << 11) + (col - DI);
              outb2[idx] = (f16)sigmf(v + aux1[col - DI]);      // lamh
            }
          }
        }
      }
    }
  }
}

// ------------------------- prep kernels -------------------------
__global__ __launch_bounds__(256) void transpose_f32_f16(
    const float* __restrict__ in, f16* __restrict__ out, int R, int C)
{
  __shared__ float t[32][33];
  const int bx = blockIdx.x * 32;
  const int by = blockIdx.y * 32;
  const int lx = threadIdx.x;
  const int ly = threadIdx.y;
#pragma unroll
  for (int i = 0; i < 32; i += 8)
    t[ly + i][lx] = in[(size_t)(by + ly + i) * C + bx + lx];
  __syncthreads();
#pragma unroll
  for (int i = 0; i < 32; i += 8)
    out[(size_t)(bx + ly + i) * R + by + lx] = (f16)t[lx][ly + i];
}

__global__ __launch_bounds__(256) void cast_f32_f16(
    const float* __restrict__ in, f16* __restrict__ out, int n)
{
  const int i = blockIdx.x * 256 + threadIdx.x;
  if (i < n) out[i] = (f16)in[i];
}

__global__ __launch_bounds__(256) void fill_init(
    float* __restrict__ h, f16* __restrict__ Aparam)
{
  const int idx = blockIdx.x * 256 + threadIdx.x;   // 0 .. 4096*2048-1
  h[idx] = 0.0f;
  const int r = idx >> 11, c = idx & 2047;
  Aparam[((size_t)r << 12) + DI + c] = (f16)0.0f;
}

// ------------------------- scan, stage 1: sc + chunk summaries (no inp write) ----------
// block = (b, ch, g): g in [0,4), 256 threads x 2 channels (float2).
// x_tilde = bx - sc*v  (h_prev cancels); inp = (1-lam)*x_tilde  (recomputed in k2).
__global__ __launch_bounds__(256) void scan_k1(
    const float* __restrict__ vraw, const f16* __restrict__ bxh,
    const f16* __restrict__ lamh,
    const float* __restrict__ ssp, const float* __restrict__ drp,
    float* __restrict__ cA, float* __restrict__ cB)
{
  const int bid = blockIdx.x;
  const int g  = bid & 3;
  const int ch = (bid >> 2) & (NCH - 1);
  const int b  = bid >> 8;
  const int tid = threadIdx.x;
  const int d = (g << 9) + (tid << 1);

  __shared__ float sc_s[CL];
  if (tid < CL) {
    const int grow = b * LSEQ + ch * CL + tid;
    float ss = 0.f, dr = 0.f;
    const f32x4* sp = (const f32x4*)&ssp[(size_t)grow << 6];
    const f32x4* dp = (const f32x4*)&drp[(size_t)grow << 6];
#pragma unroll
    for (int p = 0; p < 16; ++p) {
      const f32x4 s4 = sp[p], d4 = dp[p];
      ss += s4.x + s4.y + s4.z + s4.w;
      dr += d4.x + d4.y + d4.z + d4.w;
    }
    const float n = sqrtf(ss) + EPSF;
    sc_s[tid] = 2.0f * dr / (n * n);
  }
  __syncthreads();

  const size_t base = ((size_t)(b * LSEQ + ch * CL) << 11) + d;
  float hv0 = 0.f, hv1 = 0.f, A0 = 1.f, A1 = 1.f;
#pragma unroll 4
  for (int t = 0; t < CL; ++t) {
    const size_t ix = base + ((size_t)t << 11);
    const f16x2 la2 = *(const f16x2*)&lamh[ix];
    const f16x2 bb2 = *(const f16x2*)&bxh[ix];
    const f32x2 v   = *(const f32x2*)&vraw[ix];
    const float lax = (float)la2.x, lay = (float)la2.y;
    const float sc  = sc_s[t];
    const float i0 = (1.0f - lax) * ((float)bb2.x - sc * v.x);
    const float i1 = (1.0f - lay) * ((float)bb2.y - sc * v.y);
    hv0 = lax * hv0 + i0;
    hv1 = lay * hv1 + i1;
    A0 *= lax;
    A1 *= lay;
  }
  const size_t ci = ((size_t)(b * NCH + ch) << 11) + d;
  *(f32x2*)&cA[ci] = (f32x2){A0, A1};
  *(f32x2*)&cB[ci] = (f32x2){hv0, hv1};
}

// ------------------------- scan, stage 2: carry + recompute inp + write h/Aparam -------
// sc_s recomputation is bit-identical to k1 (same inputs, same op order).
__global__ __launch_bounds__(256) void scan_k2(
    const float* __restrict__ vraw, const f16* __restrict__ bxh,
    const f16* __restrict__ lamh,
    const float* __restrict__ ssp, const float* __restrict__ drp,
    const float* __restrict__ cA, const float* __restrict__ cB,
    float* __restrict__ h, f16* __restrict__ Aparam)
{
  const int bid = blockIdx.x;
  const int g  = bid & 3;
  const int ch = (bid >> 2) & (NCH - 1);
  const int b  = bid >> 8;
  const int tid = threadIdx.x;
  const int d = (g << 9) + (tid << 1);

  __shared__ float sc_s[CL];
  if (tid < CL) {
    const int grow = b * LSEQ + ch * CL + tid;
    float ss = 0.f, dr = 0.f;
    const f32x4* sp = (const f32x4*)&ssp[(size_t)grow << 6];
    const f32x4* dp = (const f32x4*)&drp[(size_t)grow << 6];
#pragma unroll
    for (int p = 0; p < 16; ++p) {
      const f32x4 s4 = sp[p], d4 = dp[p];
      ss += s4.x + s4.y + s4.z + s4.w;
      dr += d4.x + d4.y + d4.z + d4.w;
    }
    const float n = sqrtf(ss) + EPSF;
    sc_s[tid] = 2.0f * dr / (n * n);
  }
  __syncthreads();

  float hv0 = 0.f, hv1 = 0.f;
  for (int cc = 0; cc < ch; ++cc) {
    const size_t ci = ((size_t)(b * NCH + cc) << 11) + d;
    const f32x2 a  = *(const f32x2*)&cA[ci];
    const f32x2 bb = *(const f32x2*)&cB[ci];
    hv0 = a.x * hv0 + bb.x;
    hv1 = a.y * hv1 + bb.y;
  }

  const size_t base = ((size_t)(b * LSEQ + ch * CL) << 11) + d;
#pragma unroll 4
  for (int t = 0; t < CL; ++t) {
    const size_t ix = base + ((size_t)t << 11);
    const f16x2 la2 = *(const f16x2*)&lamh[ix];
    const f16x2 bb2 = *(const f16x2*)&bxh[ix];
    const f32x2 v   = *(const f32x2*)&vraw[ix];
    const float lax = (float)la2.x, lay = (float)la2.y;
    const float sc  = sc_s[t];
    const float i0 = (1.0f - lax) * ((float)bb2.x - sc * v.x);
    const float i1 = (1.0f - lay) * ((float)bb2.y - sc * v.y);
    hv0 = lax * hv0 + i0;
    hv1 = lay * hv1 + i1;
    *(f32x2*)&h[ix] = (f32x2){hv0, hv1};
    const int tg = ch * CL + t;
    if (tg < LSEQ - 1)
      *(f16x2*)&Aparam[(((size_t)(b * LSEQ + tg + 1)) << 12) + DI + d] =
          (f16x2){(f16)hv0, (f16)hv1};
  }
}

// ------------------------- final RMS norm (f32 in, f16 out) -------------------------
__global__ __launch_bounds__(256) void rms_norm(
    const float* __restrict__ uraw, const float* __restrict__ gn,
    f16* __restrict__ u)
{
  const int row = blockIdx.x;
  const size_t base = (size_t)row << 11;
  const int tid = threadIdx.x;
  float uv[8];
  float ss = 0.f;
#pragma unroll
  for (int k = 0; k < 8; ++k) {
    const int c = tid + (k << 8);
    uv[k] = uraw[base + c];
    ss += uv[k] * uv[k];
  }
#pragma unroll
  for (int off = 32; off; off >>= 1) ss += __shfl_xor(ss, off);
  __shared__ float sred[4];
  const int l = tid & 63, w = tid >> 6;
  if (l == 0) sred[w] = ss;
  __syncthreads();
  ss = sred[0] + sred[1] + sred[2] + sred[3];
  const float scale = 1.0f / sqrtf(ss * (1.0f / DI) + EPSF);
#pragma unroll
  for (int k = 0; k < 8; ++k) {
    const int c = tid + (k << 8);
    u[base + c] = (f16)(uv[k] * scale * gn[c]);
  }
}

// ------------------------- launch -------------------------
extern "C" void kernel_launch(void* const* d_in, const int* in_sizes, int n_in,
                              void* d_out, int out_size, void* d_ws, size_t ws_size,
                              hipStream_t stream)
{
  (void)in_sizes; (void)n_in; (void)out_size; (void)d_ws; (void)ws_size;
  const float* x      = (const float*)d_in[0];
  const float* W_in   = (const float*)d_in[1];
  const float* W_b    = (const float*)d_in[2];
  const float* W_lam  = (const float*)d_in[3];
  const float* b_lam  = (const float*)d_in[4];
  const float* W_v    = (const float*)d_in[5];
  const float* b_v    = (const float*)d_in[6];
  const float* W_c    = (const float*)d_in[7];
  const float* g_norm = (const float*)d_in[8];
  const float* W_out  = (const float*)d_in[9];
  float* out = (float*)d_out;

  char* buf = nullptr;
  hipGetSymbolAddress((void**)&buf, HIP_SYMBOL(g_buf));

  f16* Aparam = (f16*)(buf + OFF_APARAM);
  f16* Wvt    = (f16*)(buf + OFF_WVT);
  f16* Wct    = (f16*)(buf + OFF_WCT);
  f16* Wbt    = (f16*)(buf + OFF_WBT);
  f16* Wlt    = (f16*)(buf + OFF_WLT);
  f16* Wint   = (f16*)(buf + OFF_WINT);
  f16* Wot    = (f16*)(buf + OFF_WOT);
  f16* Ax     = (f16*)(buf + OFF_AX);
  f16* Zb     = (f16*)(buf + OFF_Z);
  f16* Ub     = (f16*)(buf + OFF_U);
  float* xi   = (float*)(buf + OFF_XI);
  f16* bxh    = (f16*)(buf + OFF_BXH);
  f16* lamh   = (f16*)(buf + OFF_LAMH);
  float* h    = (float*)(buf + OFF_H);
  float* vraw = (float*)(buf + OFF_VRAW);
  float* vx   = (float*)(buf + OFF_VX);
  float* ssp  = (float*)(buf + OFF_SSP);
  float* drp  = (float*)(buf + OFF_DRP);
  float* cA   = (float*)(buf + OFF_CA);
  float* cB   = (float*)(buf + OFF_CB);

  const dim3 b256(256);
  const dim3 b512(512);
  const dim3 tb(32, 8);

  fill_init<<<dim3(MROWS * DI / 256), b256, 0, stream>>>(h, Aparam);

  // weight transposes (f32 -> f16)
  transpose_f32_f16<<<dim3(128, 32), tb, 0, stream>>>(W_in,  Wint, 1024, 4096);
  transpose_f32_f16<<<dim3(64, 64), tb, 0, stream>>>(W_b,   Wbt,  2048, 2048);
  transpose_f32_f16<<<dim3(64, 64), tb, 0, stream>>>(W_lam, Wlt,  2048, 2048);
  transpose_f32_f16<<<dim3(64, 128), tb, 0, stream>>>(W_v,  Wvt,  4096, 2048);
  transpose_f32_f16<<<dim3(64, 128), tb, 0, stream>>>(W_c,  Wct,  4096, 2048);
  transpose_f32_f16<<<dim3(32, 64), tb, 0, stream>>>(W_out, Wot,  2048, 1024);
  cast_f32_f16<<<dim3(MROWS * 1024 / 256), b256, 0, stream>>>(x, Ax, MROWS * 1024);

  // xz = x @ W_in -> xi(f32) + Aparam(f16), z(f16)
  gemm_f16<1><<<dim3(32 * 32), b512, 0, stream>>>(Ax, 1024, Wint, 1024, 4096, 1024,
      xi, Aparam, Zb, nullptr, nullptr, nullptr, nullptr, nullptr, nullptr);
  // fused pair: bxh = f16(silu(x_i@W_b)*x_i); lamh = f16(sigm(x_i@W_lam+b_lam))
  gemm_f16<8><<<dim3(32 * 32), b512, 0, stream>>>(Aparam, 4096, Wbt, 2048, 4096, 2048,
      nullptr, bxh, lamh, xi, b_lam, nullptr, nullptr, nullptr, nullptr);
  // vx = x_i @ W_v[:DI] + b_v   (f32, loop-invariant)
  gemm_f16<6><<<dim3(32 * 16), b512, 0, stream>>>(Aparam, 4096, Wvt, 4096, 2048, 2048,
      vx, nullptr, nullptr, nullptr, b_v, nullptr, nullptr, nullptr, nullptr);

  for (int s = 0; s < NSTEPS; ++s) {
    // v_raw = silu(h_sh @ W_v[DI:] + vx); fused ss/dr partials vs (bxh, h)
    gemm_f16<4><<<dim3(32 * 16), b512, 0, stream>>>(Aparam + DI, 4096, Wvt + DI, 4096, 2048, 2048,
        vraw, nullptr, nullptr, h, nullptr, vx, bxh, ssp, drp);
    scan_k1<<<dim3(NBATCH * NCH * 4), b256, 0, stream>>>(vraw, bxh, lamh, ssp, drp, cA, cB);
    scan_k2<<<dim3(NBATCH * NCH * 4), b256, 0, stream>>>(vraw, bxh, lamh, ssp, drp, cA, cB, h, Aparam);
  }

  // u_raw = silu([x_i|h_sh] @ W_c) * h * silu(z)   (f32, reuses vraw)
  gemm_f16<5><<<dim3(32 * 16), b512, 0, stream>>>(Aparam, 4096, Wct, 4096, 2048, 4096,
      vraw, nullptr, nullptr, h, nullptr, nullptr, Zb, nullptr, nullptr);
  rms_norm<<<dim3(MROWS), b256, 0, stream>>>(vraw, g_norm, Ub);
  // out = u @ W_out
  gemm_f16<0><<<dim3(32 * 8), b512, 0, stream>>>(Ub, 2048, Wot, 2048, 1024, 2048,
      out, nullptr, nullptr, nullptr, nullptr, nullptr, nullptr, nullptr, nullptr);
}

// Round 13
// 3515.499 us; speedup vs baseline: 1.0072x; 1.0072x over previous
//
#include <hip/hip_runtime.h>
#include <hip/hip_bf16.h>
#include <hip/hip_fp16.h>

#define DI     2048
#define LSEQ   2048
#define NBATCH 2
#define MROWS  4096        // NBATCH * LSEQ
#define EPSF   1e-5f
#define NSTEPS 31
#define NCH    64          // scan chunks per sequence
#define CL     32          // chunk length (NCH*CL == LSEQ)

typedef float    f32x4 __attribute__((ext_vector_type(4)));
typedef float    f32x2 __attribute__((ext_vector_type(2)));
typedef _Float16 f16x8 __attribute__((ext_vector_type(8)));
typedef _Float16 f16x2 __attribute__((ext_vector_type(2)));
using f16 = _Float16;

// ------------------------- static device arena -------------------------
constexpr size_t MB = 1024ull * 1024ull;
constexpr size_t OFF_APARAM =   0 * MB;   // f16 [4096][4096] = [x_i | h_sh]   (32 MB)
constexpr size_t OFF_WVT    =  32 * MB;   // f16 [2048][4096] W_v^T            (16 MB)
constexpr size_t OFF_WCT    =  48 * MB;   // f16 [2048][4096] W_c^T            (16 MB)
constexpr size_t OFF_WBT    =  64 * MB;   // f16 [2048][2048] W_b^T            ( 8 MB)  (contiguous
constexpr size_t OFF_WLT    =  72 * MB;   // f16 [2048][2048] W_lam^T          ( 8 MB)   with WBT)
constexpr size_t OFF_WINT   =  80 * MB;   // f16 [4096][1024] W_in^T           ( 8 MB)
constexpr size_t OFF_WOT    =  88 * MB;   // f16 [1024][2048] W_out^T          ( 4 MB)
constexpr size_t OFF_AX     =  92 * MB;   // f16 [4096][1024] x                ( 8 MB)
constexpr size_t OFF_Z      = 100 * MB;   // f16 [4096][2048] z                (16 MB)
constexpr size_t OFF_U      = 116 * MB;   // f16 [4096][2048] u (normed)       (16 MB)
constexpr size_t OFF_XI     = 132 * MB;   // f32 [4096][2048] x_i              (32 MB)
constexpr size_t OFF_BXH    = 164 * MB;   // f16 b*x_i        (step-invariant) (16 MB)
constexpr size_t OFF_LAMH   = 180 * MB;   // f16 lam          (step-invariant) (16 MB)
constexpr size_t OFF_H      = 196 * MB;   // f32 h (step-varying: stays f32)   (32 MB)
constexpr size_t OFF_VRAW   = 228 * MB;   // f32 v_raw / u_raw                 (32 MB)
constexpr size_t OFF_VX     = 260 * MB;   // f32 x_i@Wv_top + b_v              (32 MB)
constexpr size_t OFF_SSP    = 292 * MB;   // f32 [4096][64] ss partials        ( 1 MB)
constexpr size_t OFF_DRP    = 293 * MB;   // f32 [4096][64] dr partials        ( 1 MB)
constexpr size_t OFF_CA     = 294 * MB;   // f32 [2][64][2048]                 ( 1 MB)
constexpr size_t OFF_CB     = 295 * MB;   //                                   ( 1 MB)
constexpr size_t OFF_SC     = 296 * MB;   // f32 [4096] per-row Householder scale (16 KB)
constexpr size_t ARENA_SZ   = 297 * MB;

__device__ __align__(256) char g_buf[ARENA_SZ];

// ------------------------- helpers -------------------------
__device__ __forceinline__ void gload16(const void* g, void* l) {
  __builtin_amdgcn_global_load_lds((const __attribute__((address_space(1))) void*)g,
                                   (__attribute__((address_space(3))) void*)l, 16, 0, 0);
}
__device__ __forceinline__ float siluf(float x) { return x / (1.0f + __expf(-x)); }
__device__ __forceinline__ float sigmf(float x) { return 1.0f / (1.0f + __expf(-x)); }

// ------------------------- GEMM: C = A(f16,MxK) * Bt(f16,NxK)^T -------------------------
// 128x128 tile, BK=64, 8 waves (512 thr), 64x32 per wave, dbuf LDS, counted vmcnt(4),
// XCD swizzle.  (Round-11 verified structure. Banned by bisect evidence: mixed-NW
// instantiations (r7/8 NaN), cooperative launches (r10 graph-capture abort),
// BK=32 (r12 regression: GEMM is grid-limited at 512 blocks, smaller BK only adds
// barriers).)
// EPI 0: outf[row*N+col] = acc
// EPI 1: split xz: col<DI -> xi(f32)+Aparam(f16); else z(f16)
// EPI 4: v = silu(acc + aux2(vx)); outf(vraw)=v; ss/dr partials (auxb=bxh f16, aux0=h f32)
// EPI 5: outf(uraw) = silu(acc) * aux0(h) * silu(auxb(z))
// EPI 6: outf(vx) = acc + aux1[col](b_v)
// EPI 8: fused pair (N=4096): col<DI -> bxh = f16(silu(acc)*aux0(xi));
//        else lamh = f16(sigm(acc + aux1[col-DI](b_lam)))
template<int EPI>
__global__ __launch_bounds__(512) void gemm_f16(
    const f16* __restrict__ A, int lda,
    const f16* __restrict__ Bt, int ldb,
    int N, int K,
    float* __restrict__ outf,
    f16* __restrict__ outb,
    f16* __restrict__ outb2,
    const float* __restrict__ aux0,
    const float* __restrict__ aux1,
    const float* __restrict__ aux2,
    const f16* __restrict__ auxb,
    float* __restrict__ ssp,
    float* __restrict__ drp)
{
  __shared__ char As[2][128 * 64 * 2];   // 16 KB per buffer
  __shared__ char Bs[2][128 * 64 * 2];

  const int tid = threadIdx.x;
  const int l   = tid & 63;
  const int w   = tid >> 6;              // 0..7
  const int wm  = (w >> 2) << 6;         // 0 or 64   (64-row wave tile)
  const int wn  = (w & 3) << 5;          // 0/32/64/96 (32-col wave tile)
  const int ntn = N >> 7;
  // XCD-aware swizzle (grid % 8 == 0 for all our shapes)
  const int nwg = (int)gridDim.x;
  const int id  = (blockIdx.x & 7) * (nwg >> 3) + (blockIdx.x >> 3);
  const int bm  = id / ntn;
  const int bn  = id % ntn;
  const size_t m0 = (size_t)bm << 7;
  const size_t n0 = (size_t)bn << 7;

  const char* Ab = (const char*)A + m0 * (size_t)(lda * 2);
  const char* Bb = (const char*)Bt + n0 * (size_t)(ldb * 2);

  f32x4 acc[4][2];
#pragma unroll
  for (int i = 0; i < 4; ++i)
#pragma unroll
    for (int j = 0; j < 2; ++j) acc[i][j] = (f32x4){0.f, 0.f, 0.f, 0.f};

  auto stage = [&](int bf, int kte) {   // kte = element offset in K; 4 loads/thread
#pragma unroll
    for (int rep = 0; rep < 2; ++rep) {
      const int o   = tid + (rep << 9);      // 16B-chunk 0..1023
      const int r   = o >> 3;                // tile row
      const int cb  = (o & 7) << 4;          // byte col in 128B row
      const int scb = cb ^ ((r & 7) << 4);   // pre-swizzled source col
      gload16(Ab + (size_t)r * (size_t)(lda * 2) + (size_t)kte * 2 + scb, &As[bf][o << 4]);
      gload16(Bb + (size_t)r * (size_t)(ldb * 2) + (size_t)kte * 2 + scb, &Bs[bf][o << 4]);
    }
  };

  const int nt = K >> 6;
  stage(0, 0);                               // prologue: tile 0 in flight (4 loads/thread)
  for (int t = 0; t < nt; ++t) {
    const int cur = t & 1;
    if (t + 1 < nt) {
      stage(cur ^ 1, (t + 1) << 6);          // prefetch next tile (4 more in flight)
      asm volatile("s_waitcnt vmcnt(4)" ::: "memory");   // wait only for tile t
    } else {
      asm volatile("s_waitcnt vmcnt(0)" ::: "memory");
    }
    __builtin_amdgcn_s_barrier();
    __builtin_amdgcn_sched_barrier(0);
    const char* Asc = As[cur];
    const char* Bsc = Bs[cur];
#pragma unroll
    for (int kk = 0; kk < 2; ++kk) {
      f16x8 af[4], bfr[2];
      const int kb = (kk << 6) + ((l >> 4) << 4);
#pragma unroll
      for (int i = 0; i < 4; ++i) {
        const int Ra = wm + (i << 4) + (l & 15);
        af[i] = *(const f16x8*)(Asc + (Ra << 7) + (kb ^ ((Ra & 7) << 4)));
      }
#pragma unroll
      for (int j = 0; j < 2; ++j) {
        const int Rb = wn + (j << 4) + (l & 15);
        bfr[j] = *(const f16x8*)(Bsc + (Rb << 7) + (kb ^ ((Rb & 7) << 4)));
      }
#pragma unroll
      for (int i = 0; i < 4; ++i)
#pragma unroll
        for (int j = 0; j < 2; ++j)
          acc[i][j] = __builtin_amdgcn_mfma_f32_16x16x32_f16(af[i], bfr[j], acc[i][j], 0, 0, 0);
    }
    __builtin_amdgcn_sched_barrier(0);
    __builtin_amdgcn_s_barrier();
    __builtin_amdgcn_sched_barrier(0);
  }

  // epilogue: C/D layout col=lane&15, row=(lane>>4)*4+reg
  if constexpr (EPI == 4) {
#pragma unroll
    for (int i = 0; i < 4; ++i) {
#pragma unroll
      for (int rg = 0; rg < 4; ++rg) {
        const size_t row = m0 + wm + (i << 4) + ((l >> 4) << 2) + rg;
        float ssl = 0.f, drl = 0.f;
#pragma unroll
        for (int j = 0; j < 2; ++j) {
          const size_t col = n0 + wn + (j << 4) + (l & 15);
          const size_t idx = (row << 11) + col;
          const float v = siluf(acc[i][j][rg] + aux2[idx]);
          outf[idx] = v;
          ssl += v * v;
          drl += ((float)auxb[idx] - aux0[idx]) * v;   // (bx - h_prev) * v
        }
#pragma unroll
        for (int m = 8; m; m >>= 1) {           // reduce within 16-lane col group
          ssl += __shfl_xor(ssl, m);
          drl += __shfl_xor(drl, m);
        }
        if ((l & 15) == 0) {
          const int nb = (int)((n0 + wn) >> 5);  // 0..63 (32-col slots)
          ssp[(row << 6) + nb] = ssl;
          drp[(row << 6) + nb] = drl;
        }
      }
    }
  } else {
#pragma unroll
    for (int i = 0; i < 4; ++i) {
#pragma unroll
      for (int j = 0; j < 2; ++j) {
#pragma unroll
        for (int rg = 0; rg < 4; ++rg) {
          const size_t row = m0 + wm + (i << 4) + ((l >> 4) << 2) + rg;
          const size_t col = n0 + wn + (j << 4) + (l & 15);
          const float v = acc[i][j][rg];
          if constexpr (EPI == 0) {
            outf[row * (size_t)N + col] = v;
          } else if constexpr (EPI == 1) {
            if (col < DI) {
              outf[(row << 11) + col] = v;
              outb[(row << 12) + col] = (f16)v;
            } else {
              outb2[(row << 11) + (col - DI)] = (f16)v;
            }
          } else if constexpr (EPI == 5) {
            const size_t idx = (row << 11) + col;
            outf[idx] = siluf(v) * aux0[idx] * siluf((float)auxb[idx]);
          } else if constexpr (EPI == 6) {
            const size_t idx = (row << 11) + col;
            outf[idx] = v + aux1[col];
          } else if constexpr (EPI == 8) {
            if (col < DI) {
              const size_t idx = (row << 11) + col;
              outb[idx] = (f16)(siluf(v) * aux0[idx]);          // bxh
            } else {
              const size_t idx = (row << 11) + (col - DI);
              outb2[idx] = (f16)sigmf(v + aux1[col - DI]);      // lamh
            }
          }
        }
      }
    }
  }
}

// ------------------------- prep kernels -------------------------
__global__ __launch_bounds__(256) void transpose_f32_f16(
    const float* __restrict__ in, f16* __restrict__ out, int R, int C)
{
  __shared__ float t[32][33];
  const int bx = blockIdx.x * 32;
  const int by = blockIdx.y * 32;
  const int lx = threadIdx.x;
  const int ly = threadIdx.y;
#pragma unroll
  for (int i = 0; i < 32; i += 8)
    t[ly + i][lx] = in[(size_t)(by + ly + i) * C + bx + lx];
  __syncthreads();
#pragma unroll
  for (int i = 0; i < 32; i += 8)
    out[(size_t)(bx + ly + i) * R + by + lx] = (f16)t[lx][ly + i];
}

__global__ __launch_bounds__(256) void cast_f32_f16(
    const float* __restrict__ in, f16* __restrict__ out, int n)
{
  const int i = blockIdx.x * 256 + threadIdx.x;
  if (i < n) out[i] = (f16)in[i];
}

__global__ __launch_bounds__(256) void fill_init(
    float* __restrict__ h, f16* __restrict__ Aparam)
{
  const int idx = blockIdx.x * 256 + threadIdx.x;   // 0 .. 4096*2048-1
  h[idx] = 0.0f;
  const int r = idx >> 11, c = idx & 2047;
  Aparam[((size_t)r << 12) + DI + c] = (f16)0.0f;
}

// ------------------------- sc precompute: per-row Householder scale ---------------------
// Summation order IDENTICAL to the previous inline k1/k2 version -> bit-identical sc.
__global__ __launch_bounds__(256) void sc_pre(
    const float* __restrict__ ssp, const float* __restrict__ drp,
    float* __restrict__ sc)
{
  const int row = blockIdx.x * 256 + threadIdx.x;   // 0..4095
  float ss = 0.f, dr = 0.f;
  const f32x4* sp = (const f32x4*)&ssp[(size_t)row << 6];
  const f32x4* dp = (const f32x4*)&drp[(size_t)row << 6];
#pragma unroll
  for (int p = 0; p < 16; ++p) {
    const f32x4 s4 = sp[p], d4 = dp[p];
    ss += s4.x + s4.y + s4.z + s4.w;
    dr += d4.x + d4.y + d4.z + d4.w;
  }
  const float n = sqrtf(ss) + EPSF;
  sc[row] = 2.0f * dr / (n * n);
}

// ------------------------- scan, stage 1: chunk summaries (no inp write) ----------------
// block = (b, ch, g): g in [0,4), 256 threads x 2 channels (float2).
// x_tilde = bx - sc*v  (h_prev cancels); inp = (1-lam)*x_tilde  (recomputed in k2).
__global__ __launch_bounds__(256) void scan_k1(
    const float* __restrict__ vraw, const f16* __restrict__ bxh,
    const f16* __restrict__ lamh, const float* __restrict__ sc,
    float* __restrict__ cA, float* __restrict__ cB)
{
  const int bid = blockIdx.x;
  const int g  = bid & 3;
  const int ch = (bid >> 2) & (NCH - 1);
  const int b  = bid >> 8;
  const int tid = threadIdx.x;
  const int d = (g << 9) + (tid << 1);

  __shared__ float sc_s[CL];
  if (tid < CL) sc_s[tid] = sc[b * LSEQ + ch * CL + tid];
  __syncthreads();

  const size_t base = ((size_t)(b * LSEQ + ch * CL) << 11) + d;
  float hv0 = 0.f, hv1 = 0.f, A0 = 1.f, A1 = 1.f;
#pragma unroll 4
  for (int t = 0; t < CL; ++t) {
    const size_t ix = base + ((size_t)t << 11);
    const f16x2 la2 = *(const f16x2*)&lamh[ix];
    const f16x2 bb2 = *(const f16x2*)&bxh[ix];
    const f32x2 v   = *(const f32x2*)&vraw[ix];
    const float lax = (float)la2.x, lay = (float)la2.y;
    const float scv = sc_s[t];
    const float i0 = (1.0f - lax) * ((float)bb2.x - scv * v.x);
    const float i1 = (1.0f - lay) * ((float)bb2.y - scv * v.y);
    hv0 = lax * hv0 + i0;
    hv1 = lay * hv1 + i1;
    A0 *= lax;
    A1 *= lay;
  }
  const size_t ci = ((size_t)(b * NCH + ch) << 11) + d;
  *(f32x2*)&cA[ci] = (f32x2){A0, A1};
  *(f32x2*)&cB[ci] = (f32x2){hv0, hv1};
}

// ------------------------- scan, stage 2: carry + recompute inp + write h/Aparam -------
// inp recomputation is bit-identical to k1 (same inputs, same op order).
__global__ __launch_bounds__(256) void scan_k2(
    const float* __restrict__ vraw, const f16* __restrict__ bxh,
    const f16* __restrict__ lamh, const float* __restrict__ sc,
    const float* __restrict__ cA, const float* __restrict__ cB,
    float* __restrict__ h, f16* __restrict__ Aparam)
{
  const int bid = blockIdx.x;
  const int g  = bid & 3;
  const int ch = (bid >> 2) & (NCH - 1);
  const int b  = bid >> 8;
  const int tid = threadIdx.x;
  const int d = (g << 9) + (tid << 1);

  __shared__ float sc_s[CL];
  if (tid < CL) sc_s[tid] = sc[b * LSEQ + ch * CL + tid];
  __syncthreads();

  float hv0 = 0.f, hv1 = 0.f;
  for (int cc = 0; cc < ch; ++cc) {
    const size_t ci = ((size_t)(b * NCH + cc) << 11) + d;
    const f32x2 a  = *(const f32x2*)&cA[ci];
    const f32x2 bb = *(const f32x2*)&cB[ci];
    hv0 = a.x * hv0 + bb.x;
    hv1 = a.y * hv1 + bb.y;
  }

  const size_t base = ((size_t)(b * LSEQ + ch * CL) << 11) + d;
#pragma unroll 4
  for (int t = 0; t < CL; ++t) {
    const size_t ix = base + ((size_t)t << 11);
    const f16x2 la2 = *(const f16x2*)&lamh[ix];
    const f16x2 bb2 = *(const f16x2*)&bxh[ix];
    const f32x2 v   = *(const f32x2*)&vraw[ix];
    const float lax = (float)la2.x, lay = (float)la2.y;
    const float scv = sc_s[t];
    const float i0 = (1.0f - lax) * ((float)bb2.x - scv * v.x);
    const float i1 = (1.0f - lay) * ((float)bb2.y - scv * v.y);
    hv0 = lax * hv0 + i0;
    hv1 = lay * hv1 + i1;
    *(f32x2*)&h[ix] = (f32x2){hv0, hv1};
    const int tg = ch * CL + t;
    if (tg < LSEQ - 1)
      *(f16x2*)&Aparam[(((size_t)(b * LSEQ + tg + 1)) << 12) + DI + d] =
          (f16x2){(f16)hv0, (f16)hv1};
  }
}

// ------------------------- final RMS norm (f32 in, f16 out) -------------------------
__global__ __launch_bounds__(256) void rms_norm(
    const float* __restrict__ uraw, const float* __restrict__ gn,
    f16* __restrict__ u)
{
  const int row = blockIdx.x;
  const size_t base = (size_t)row << 11;
  const int tid = threadIdx.x;
  float uv[8];
  float ss = 0.f;
#pragma unroll
  for (int k = 0; k < 8; ++k) {
    const int c = tid + (k << 8);
    uv[k] = uraw[base + c];
    ss += uv[k] * uv[k];
  }
#pragma unroll
  for (int off = 32; off; off >>= 1) ss += __shfl_xor(ss, off);
  __shared__ float sred[4];
  const int l = tid & 63, w = tid >> 6;
  if (l == 0) sred[w] = ss;
  __syncthreads();
  ss = sred[0] + sred[1] + sred[2] + sred[3];
  const float scale = 1.0f / sqrtf(ss * (1.0f / DI) + EPSF);
#pragma unroll
  for (int k = 0; k < 8; ++k) {
    const int c = tid + (k << 8);
    u[base + c] = (f16)(uv[k] * scale * gn[c]);
  }
}

// ------------------------- launch -------------------------
extern "C" void kernel_launch(void* const* d_in, const int* in_sizes, int n_in,
                              void* d_out, int out_size, void* d_ws, size_t ws_size,
                              hipStream_t stream)
{
  (void)in_sizes; (void)n_in; (void)out_size; (void)d_ws; (void)ws_size;
  const float* x      = (const float*)d_in[0];
  const float* W_in   = (const float*)d_in[1];
  const float* W_b    = (const float*)d_in[2];
  const float* W_lam  = (const float*)d_in[3];
  const float* b_lam  = (const float*)d_in[4];
  const float* W_v    = (const float*)d_in[5];
  const float* b_v    = (const float*)d_in[6];
  const float* W_c    = (const float*)d_in[7];
  const float* g_norm = (const float*)d_in[8];
  const float* W_out  = (const float*)d_in[9];
  float* out = (float*)d_out;

  char* buf = nullptr;
  hipGetSymbolAddress((void**)&buf, HIP_SYMBOL(g_buf));

  f16* Aparam = (f16*)(buf + OFF_APARAM);
  f16* Wvt    = (f16*)(buf + OFF_WVT);
  f16* Wct    = (f16*)(buf + OFF_WCT);
  f16* Wbt    = (f16*)(buf + OFF_WBT);
  f16* Wlt    = (f16*)(buf + OFF_WLT);
  f16* Wint   = (f16*)(buf + OFF_WINT);
  f16* Wot    = (f16*)(buf + OFF_WOT);
  f16* Ax     = (f16*)(buf + OFF_AX);
  f16* Zb     = (f16*)(buf + OFF_Z);
  f16* Ub     = (f16*)(buf + OFF_U);
  float* xi   = (float*)(buf + OFF_XI);
  f16* bxh    = (f16*)(buf + OFF_BXH);
  f16* lamh   = (f16*)(buf + OFF_LAMH);
  float* h    = (float*)(buf + OFF_H);
  float* vraw = (float*)(buf + OFF_VRAW);
  float* vx   = (float*)(buf + OFF_VX);
  float* ssp  = (float*)(buf + OFF_SSP);
  float* drp  = (float*)(buf + OFF_DRP);
  float* cA   = (float*)(buf + OFF_CA);
  float* cB   = (float*)(buf + OFF_CB);
  float* scb  = (float*)(buf + OFF_SC);

  const dim3 b256(256);
  const dim3 b512(512);
  const dim3 tb(32, 8);

  fill_init<<<dim3(MROWS * DI / 256), b256, 0, stream>>>(h, Aparam);

  // weight transposes (f32 -> f16)
  transpose_f32_f16<<<dim3(128, 32), tb, 0, stream>>>(W_in,  Wint, 1024, 4096);
  transpose_f32_f16<<<dim3(64, 64), tb, 0, stream>>>(W_b,   Wbt,  2048, 2048);
  transpose_f32_f16<<<dim3(64, 64), tb, 0, stream>>>(W_lam, Wlt,  2048, 2048);
  transpose_f32_f16<<<dim3(64, 128), tb, 0, stream>>>(W_v,  Wvt,  4096, 2048);
  transpose_f32_f16<<<dim3(64, 128), tb, 0, stream>>>(W_c,  Wct,  4096, 2048);
  transpose_f32_f16<<<dim3(32, 64), tb, 0, stream>>>(W_out, Wot,  2048, 1024);
  cast_f32_f16<<<dim3(MROWS * 1024 / 256), b256, 0, stream>>>(x, Ax, MROWS * 1024);

  // xz = x @ W_in -> xi(f32) + Aparam(f16), z(f16)
  gemm_f16<1><<<dim3(32 * 32), b512, 0, stream>>>(Ax, 1024, Wint, 1024, 4096, 1024,
      xi, Aparam, Zb, nullptr, nullptr, nullptr, nullptr, nullptr, nullptr);
  // fused pair: bxh = f16(silu(x_i@W_b)*x_i); lamh = f16(sigm(x_i@W_lam+b_lam))
  gemm_f16<8><<<dim3(32 * 32), b512, 0, stream>>>(Aparam, 4096, Wbt, 2048, 4096, 2048,
      nullptr, bxh, lamh, xi, b_lam, nullptr, nullptr, nullptr, nullptr);
  // vx = x_i @ W_v[:DI] + b_v   (f32, loop-invariant)
  gemm_f16<6><<<dim3(32 * 16), b512, 0, stream>>>(Aparam, 4096, Wvt, 4096, 2048, 2048,
      vx, nullptr, nullptr, nullptr, b_v, nullptr, nullptr, nullptr, nullptr);

  for (int s = 0; s < NSTEPS; ++s) {
    // v_raw = silu(h_sh @ W_v[DI:] + vx); fused ss/dr partials vs (bxh, h)
    gemm_f16<4><<<dim3(32 * 16), b512, 0, stream>>>(Aparam + DI, 4096, Wvt + DI, 4096, 2048, 2048,
        vraw, nullptr, nullptr, h, nullptr, vx, bxh, ssp, drp);
    sc_pre<<<dim3(16), b256, 0, stream>>>(ssp, drp, scb);
    scan_k1<<<dim3(NBATCH * NCH * 4), b256, 0, stream>>>(vraw, bxh, lamh, scb, cA, cB);
    scan_k2<<<dim3(NBATCH * NCH * 4), b256, 0, stream>>>(vraw, bxh, lamh, scb, cA, cB, h, Aparam);
  }

  // u_raw = silu([x_i|h_sh] @ W_c) * h * silu(z)   (f32, reuses vraw)
  gemm_f16<5><<<dim3(32 * 16), b512, 0, stream>>>(Aparam, 4096, Wct, 4096, 2048, 4096,
      vraw, nullptr, nullptr, h, nullptr, nullptr, Zb, nullptr, nullptr);
  rms_norm<<<dim3(MROWS), b256, 0, stream>>>(vraw, g_norm, Ub);
  // out = u @ W_out
  gemm_f16<0><<<dim3(32 * 8), b512, 0, stream>>>(Ub, 2048, Wot, 2048, 1024, 2048,
      out, nullptr, nullptr, nullptr, nullptr, nullptr, nullptr, nullptr, nullptr);
}

// Round 14
// 3355.129 us; speedup vs baseline: 1.0553x; 1.0478x over previous
//
#include <hip/hip_runtime.h>
#include <hip/hip_bf16.h>
#include <hip/hip_fp16.h>

#define DI     2048
#define LSEQ   2048
#define NBATCH 2
#define MROWS  4096        // NBATCH * LSEQ
#define EPSF   1e-5f
#define NSTEPS 31
#define NCH    64          // scan chunks per sequence
#define CL     32          // chunk length (NCH*CL == LSEQ)

typedef float    f32x4 __attribute__((ext_vector_type(4)));
typedef float    f32x2 __attribute__((ext_vector_type(2)));
typedef _Float16 f16x8 __attribute__((ext_vector_type(8)));
typedef _Float16 f16x2 __attribute__((ext_vector_type(2)));
using f16 = _Float16;

// ------------------------- static device arena -------------------------
constexpr size_t MB = 1024ull * 1024ull;
constexpr size_t OFF_APARAM =   0 * MB;   // f16 [4096][4096] = [x_i | h_sh]   (32 MB)
constexpr size_t OFF_WVT    =  32 * MB;   // f16 [2048][4096] W_v^T            (16 MB)
constexpr size_t OFF_WCT    =  48 * MB;   // f16 [2048][4096] W_c^T            (16 MB)
constexpr size_t OFF_WBT    =  64 * MB;   // f16 [2048][2048] W_b^T            ( 8 MB)  (contiguous
constexpr size_t OFF_WLT    =  72 * MB;   // f16 [2048][2048] W_lam^T          ( 8 MB)   with WBT)
constexpr size_t OFF_WINT   =  80 * MB;   // f16 [4096][1024] W_in^T           ( 8 MB)
constexpr size_t OFF_WOT    =  88 * MB;   // f16 [1024][2048] W_out^T          ( 4 MB)
constexpr size_t OFF_AX     =  92 * MB;   // f16 [4096][1024] x                ( 8 MB)
constexpr size_t OFF_Z      = 100 * MB;   // f16 [4096][2048] z                (16 MB)
constexpr size_t OFF_U      = 116 * MB;   // f16 [4096][2048] u (normed)       (16 MB)
constexpr size_t OFF_XI     = 132 * MB;   // f32 [4096][2048] x_i              (32 MB)
constexpr size_t OFF_BXH    = 164 * MB;   // f16 b*x_i        (step-invariant) (16 MB)
constexpr size_t OFF_LAMH   = 180 * MB;   // f16 lam          (step-invariant) (16 MB)
constexpr size_t OFF_H      = 196 * MB;   // f32 h (step-varying: stays f32)   (32 MB)
constexpr size_t OFF_VRAW   = 228 * MB;   // f32 v_raw / u_raw                 (32 MB)
constexpr size_t OFF_VX     = 260 * MB;   // f32 x_i@Wv_top + b_v              (32 MB)
constexpr size_t OFF_SSP    = 292 * MB;   // f32 [4096][64] ss partials        ( 1 MB)
constexpr size_t OFF_DRP    = 293 * MB;   // f32 [4096][64] dr partials        ( 1 MB)
constexpr size_t OFF_CA     = 294 * MB;   // f32 [2][64][2048]                 ( 1 MB)
constexpr size_t OFF_CB     = 295 * MB;   //                                   ( 1 MB)
constexpr size_t ARENA_SZ   = 296 * MB;

__device__ __align__(256) char g_buf[ARENA_SZ];

// ------------------------- helpers -------------------------
__device__ __forceinline__ void gload16(const void* g, void* l) {
  __builtin_amdgcn_global_load_lds((const __attribute__((address_space(1))) void*)g,
                                   (__attribute__((address_space(3))) void*)l, 16, 0, 0);
}
__device__ __forceinline__ float siluf(float x) { return x / (1.0f + __expf(-x)); }
__device__ __forceinline__ float sigmf(float x) { return 1.0f / (1.0f + __expf(-x)); }

// ------------------------- GEMM: C = A(f16,MxK) * Bt(f16,NxK)^T -------------------------
// 128x128 tile, BK=64, 8 waves (512 thr), 64x32 per wave, dbuf LDS, counted vmcnt(4),
// XCD swizzle.  ROUND-11 VERIFIED OPTIMUM — do not perturb without bisect discipline.
// Banned by bisect evidence: mixed-NW instantiations (r7/8 NaN), cooperative launches
// (r10 graph-capture abort), BK=32 (r12: grid-limited, −5%), extra per-step launches
// (r13 sc_pre: +5 µs/step launch gap).
// EPI 0: outf[row*N+col] = acc
// EPI 1: split xz: col<DI -> xi(f32)+Aparam(f16); else z(f16)
// EPI 4: v = silu(acc + aux2(vx)); outf(vraw)=v; ss/dr partials (auxb=bxh f16, aux0=h f32)
// EPI 5: outf(uraw) = silu(acc) * aux0(h) * silu(auxb(z))
// EPI 6: outf(vx) = acc + aux1[col](b_v)
// EPI 8: fused pair (N=4096): col<DI -> bxh = f16(silu(acc)*aux0(xi));
//        else lamh = f16(sigm(acc + aux1[col-DI](b_lam)))
template<int EPI>
__global__ __launch_bounds__(512) void gemm_f16(
    const f16* __restrict__ A, int lda,
    const f16* __restrict__ Bt, int ldb,
    int N, int K,
    float* __restrict__ outf,
    f16* __restrict__ outb,
    f16* __restrict__ outb2,
    const float* __restrict__ aux0,
    const float* __restrict__ aux1,
    const float* __restrict__ aux2,
    const f16* __restrict__ auxb,
    float* __restrict__ ssp,
    float* __restrict__ drp)
{
  __shared__ char As[2][128 * 64 * 2];   // 16 KB per buffer
  __shared__ char Bs[2][128 * 64 * 2];

  const int tid = threadIdx.x;
  const int l   = tid & 63;
  const int w   = tid >> 6;              // 0..7
  const int wm  = (w >> 2) << 6;         // 0 or 64   (64-row wave tile)
  const int wn  = (w & 3) << 5;          // 0/32/64/96 (32-col wave tile)
  const int ntn = N >> 7;
  // XCD-aware swizzle (grid % 8 == 0 for all our shapes)
  const int nwg = (int)gridDim.x;
  const int id  = (blockIdx.x & 7) * (nwg >> 3) + (blockIdx.x >> 3);
  const int bm  = id / ntn;
  const int bn  = id % ntn;
  const size_t m0 = (size_t)bm << 7;
  const size_t n0 = (size_t)bn << 7;

  const char* Ab = (const char*)A + m0 * (size_t)(lda * 2);
  const char* Bb = (const char*)Bt + n0 * (size_t)(ldb * 2);

  f32x4 acc[4][2];
#pragma unroll
  for (int i = 0; i < 4; ++i)
#pragma unroll
    for (int j = 0; j < 2; ++j) acc[i][j] = (f32x4){0.f, 0.f, 0.f, 0.f};

  auto stage = [&](int bf, int kte) {   // kte = element offset in K; 4 loads/thread
#pragma unroll
    for (int rep = 0; rep < 2; ++rep) {
      const int o   = tid + (rep << 9);      // 16B-chunk 0..1023
      const int r   = o >> 3;                // tile row
      const int cb  = (o & 7) << 4;          // byte col in 128B row
      const int scb = cb ^ ((r & 7) << 4);   // pre-swizzled source col
      gload16(Ab + (size_t)r * (size_t)(lda * 2) + (size_t)kte * 2 + scb, &As[bf][o << 4]);
      gload16(Bb + (size_t)r * (size_t)(ldb * 2) + (size_t)kte * 2 + scb, &Bs[bf][o << 4]);
    }
  };

  const int nt = K >> 6;
  stage(0, 0);                               // prologue: tile 0 in flight (4 loads/thread)
  for (int t = 0; t < nt; ++t) {
    const int cur = t & 1;
    if (t + 1 < nt) {
      stage(cur ^ 1, (t + 1) << 6);          // prefetch next tile (4 more in flight)
      asm volatile("s_waitcnt vmcnt(4)" ::: "memory");   // wait only for tile t
    } else {
      asm volatile("s_waitcnt vmcnt(0)" ::: "memory");
    }
    __builtin_amdgcn_s_barrier();
    __builtin_amdgcn_sched_barrier(0);
    const char* Asc = As[cur];
    const char* Bsc = Bs[cur];
#pragma unroll
    for (int kk = 0; kk < 2; ++kk) {
      f16x8 af[4], bfr[2];
      const int kb = (kk << 6) + ((l >> 4) << 4);
#pragma unroll
      for (int i = 0; i < 4; ++i) {
        const int Ra = wm + (i << 4) + (l & 15);
        af[i] = *(const f16x8*)(Asc + (Ra << 7) + (kb ^ ((Ra & 7) << 4)));
      }
#pragma unroll
      for (int j = 0; j < 2; ++j) {
        const int Rb = wn + (j << 4) + (l & 15);
        bfr[j] = *(const f16x8*)(Bsc + (Rb << 7) + (kb ^ ((Rb & 7) << 4)));
      }
#pragma unroll
      for (int i = 0; i < 4; ++i)
#pragma unroll
        for (int j = 0; j < 2; ++j)
          acc[i][j] = __builtin_amdgcn_mfma_f32_16x16x32_f16(af[i], bfr[j], acc[i][j], 0, 0, 0);
    }
    __builtin_amdgcn_sched_barrier(0);
    __builtin_amdgcn_s_barrier();
    __builtin_amdgcn_sched_barrier(0);
  }

  // epilogue: C/D layout col=lane&15, row=(lane>>4)*4+reg
  if constexpr (EPI == 4) {
#pragma unroll
    for (int i = 0; i < 4; ++i) {
#pragma unroll
      for (int rg = 0; rg < 4; ++rg) {
        const size_t row = m0 + wm + (i << 4) + ((l >> 4) << 2) + rg;
        float ssl = 0.f, drl = 0.f;
#pragma unroll
        for (int j = 0; j < 2; ++j) {
          const size_t col = n0 + wn + (j << 4) + (l & 15);
          const size_t idx = (row << 11) + col;
          const float v = siluf(acc[i][j][rg] + aux2[idx]);
          outf[idx] = v;
          ssl += v * v;
          drl += ((float)auxb[idx] - aux0[idx]) * v;   // (bx - h_prev) * v
        }
#pragma unroll
        for (int m = 8; m; m >>= 1) {           // reduce within 16-lane col group
          ssl += __shfl_xor(ssl, m);
          drl += __shfl_xor(drl, m);
        }
        if ((l & 15) == 0) {
          const int nb = (int)((n0 + wn) >> 5);  // 0..63 (32-col slots)
          ssp[(row << 6) + nb] = ssl;
          drp[(row << 6) + nb] = drl;
        }
      }
    }
  } else {
#pragma unroll
    for (int i = 0; i < 4; ++i) {
#pragma unroll
      for (int j = 0; j < 2; ++j) {
#pragma unroll
        for (int rg = 0; rg < 4; ++rg) {
          const size_t row = m0 + wm + (i << 4) + ((l >> 4) << 2) + rg;
          const size_t col = n0 + wn + (j << 4) + (l & 15);
          const float v = acc[i][j][rg];
          if constexpr (EPI == 0) {
            outf[row * (size_t)N + col] = v;
          } else if constexpr (EPI == 1) {
            if (col < DI) {
              outf[(row << 11) + col] = v;
              outb[(row << 12) + col] = (f16)v;
            } else {
              outb2[(row << 11) + (col - DI)] = (f16)v;
            }
          } else if constexpr (EPI == 5) {
            const size_t idx = (row << 11) + col;
            outf[idx] = siluf(v) * aux0[idx] * siluf((float)auxb[idx]);
          } else if constexpr (EPI == 6) {
            const size_t idx = (row << 11) + col;
            outf[idx] = v + aux1[col];
          } else if constexpr (EPI == 8) {
            if (col < DI) {
              const size_t idx = (row << 11) + col;
              outb[idx] = (f16)(siluf(v) * aux0[idx]);          // bxh
            } else {
              const size_t idx = (row << 11) + (col - DI);
              outb2[idx] = (f16)sigmf(v + aux1[col - DI]);      // lamh
            }
          }
        }
      }
    }
  }
}

// ------------------------- prep kernels -------------------------
__global__ __launch_bounds__(256) void transpose_f32_f16(
    const float* __restrict__ in, f16* __restrict__ out, int R, int C)
{
  __shared__ float t[32][33];
  const int bx = blockIdx.x * 32;
  const int by = blockIdx.y * 32;
  const int lx = threadIdx.x;
  const int ly = threadIdx.y;
#pragma unroll
  for (int i = 0; i < 32; i += 8)
    t[ly + i][lx] = in[(size_t)(by + ly + i) * C + bx + lx];
  __syncthreads();
#pragma unroll
  for (int i = 0; i < 32; i += 8)
    out[(size_t)(bx + ly + i) * R + by + lx] = (f16)t[lx][ly + i];
}

__global__ __launch_bounds__(256) void cast_f32_f16(
    const float* __restrict__ in, f16* __restrict__ out, int n)
{
  const int i = blockIdx.x * 256 + threadIdx.x;
  if (i < n) out[i] = (f16)in[i];
}

__global__ __launch_bounds__(256) void fill_init(
    float* __restrict__ h, f16* __restrict__ Aparam)
{
  const int idx = blockIdx.x * 256 + threadIdx.x;   // 0 .. 4096*2048-1
  h[idx] = 0.0f;
  const int r = idx >> 11, c = idx & 2047;
  Aparam[((size_t)r << 12) + DI + c] = (f16)0.0f;
}

// ------------------------- scan, stage 1: sc + chunk summaries (no inp write) ----------
// block = (b, ch, g): g in [0,4), 256 threads x 2 channels (float2).
// x_tilde = bx - sc*v  (h_prev cancels); inp = (1-lam)*x_tilde  (recomputed in k2).
__global__ __launch_bounds__(256) void scan_k1(
    const float* __restrict__ vraw, const f16* __restrict__ bxh,
    const f16* __restrict__ lamh,
    const float* __restrict__ ssp, const float* __restrict__ drp,
    float* __restrict__ cA, float* __restrict__ cB)
{
  const int bid = blockIdx.x;
  const int g  = bid & 3;
  const int ch = (bid >> 2) & (NCH - 1);
  const int b  = bid >> 8;
  const int tid = threadIdx.x;
  const int d = (g << 9) + (tid << 1);

  __shared__ float sc_s[CL];
  if (tid < CL) {
    const int grow = b * LSEQ + ch * CL + tid;
    float ss = 0.f, dr = 0.f;
    const f32x4* sp = (const f32x4*)&ssp[(size_t)grow << 6];
    const f32x4* dp = (const f32x4*)&drp[(size_t)grow << 6];
#pragma unroll
    for (int p = 0; p < 16; ++p) {
      const f32x4 s4 = sp[p], d4 = dp[p];
      ss += s4.x + s4.y + s4.z + s4.w;
      dr += d4.x + d4.y + d4.z + d4.w;
    }
    const float n = sqrtf(ss) + EPSF;
    sc_s[tid] = 2.0f * dr / (n * n);
  }
  __syncthreads();

  const size_t base = ((size_t)(b * LSEQ + ch * CL) << 11) + d;
  float hv0 = 0.f, hv1 = 0.f, A0 = 1.f, A1 = 1.f;
#pragma unroll 4
  for (int t = 0; t < CL; ++t) {
    const size_t ix = base + ((size_t)t << 11);
    const f16x2 la2 = *(const f16x2*)&lamh[ix];
    const f16x2 bb2 = *(const f16x2*)&bxh[ix];
    const f32x2 v   = *(const f32x2*)&vraw[ix];
    const float lax = (float)la2.x, lay = (float)la2.y;
    const float sc  = sc_s[t];
    const float i0 = (1.0f - lax) * ((float)bb2.x - sc * v.x);
    const float i1 = (1.0f - lay) * ((float)bb2.y - sc * v.y);
    hv0 = lax * hv0 + i0;
    hv1 = lay * hv1 + i1;
    A0 *= lax;
    A1 *= lay;
  }
  const size_t ci = ((size_t)(b * NCH + ch) << 11) + d;
  *(f32x2*)&cA[ci] = (f32x2){A0, A1};
  *(f32x2*)&cB[ci] = (f32x2){hv0, hv1};
}

// ------------------------- scan, stage 2: carry + recompute inp + write h/Aparam -------
// sc_s recomputation is bit-identical to k1 (same inputs, same op order).
__global__ __launch_bounds__(256) void scan_k2(
    const float* __restrict__ vraw, const f16* __restrict__ bxh,
    const f16* __restrict__ lamh,
    const float* __restrict__ ssp, const float* __restrict__ drp,
    const float* __restrict__ cA, const float* __restrict__ cB,
    float* __restrict__ h, f16* __restrict__ Aparam)
{
  const int bid = blockIdx.x;
  const int g  = bid & 3;
  const int ch = (bid >> 2) & (NCH - 1);
  const int b  = bid >> 8;
  const int tid = threadIdx.x;
  const int d = (g << 9) + (tid << 1);

  __shared__ float sc_s[CL];
  if (tid < CL) {
    const int grow = b * LSEQ + ch * CL + tid;
    float ss = 0.f, dr = 0.f;
    const f32x4* sp = (const f32x4*)&ssp[(size_t)grow << 6];
    const f32x4* dp = (const f32x4*)&drp[(size_t)grow << 6];
#pragma unroll
    for (int p = 0; p < 16; ++p) {
      const f32x4 s4 = sp[p], d4 = dp[p];
      ss += s4.x + s4.y + s4.z + s4.w;
      dr += d4.x + d4.y + d4.z + d4.w;
    }
    const float n = sqrtf(ss) + EPSF;
    sc_s[tid] = 2.0f * dr / (n * n);
  }
  __syncthreads();

  float hv0 = 0.f, hv1 = 0.f;
  for (int cc = 0; cc < ch; ++cc) {
    const size_t ci = ((size_t)(b * NCH + cc) << 11) + d;
    const f32x2 a  = *(const f32x2*)&cA[ci];
    const f32x2 bb = *(const f32x2*)&cB[ci];
    hv0 = a.x * hv0 + bb.x;
    hv1 = a.y * hv1 + bb.y;
  }

  const size_t base = ((size_t)(b * LSEQ + ch * CL) << 11) + d;
#pragma unroll 4
  for (int t = 0; t < CL; ++t) {
    const size_t ix = base + ((size_t)t << 11);
    const f16x2 la2 = *(const f16x2*)&lamh[ix];
    const f16x2 bb2 = *(const f16x2*)&bxh[ix];
    const f32x2 v   = *(const f32x2*)&vraw[ix];
    const float lax = (float)la2.x, lay = (float)la2.y;
    const float sc  = sc_s[t];
    const float i0 = (1.0f - lax) * ((float)bb2.x - sc * v.x);
    const float i1 = (1.0f - lay) * ((float)bb2.y - sc * v.y);
    hv0 = lax * hv0 + i0;
    hv1 = lay * hv1 + i1;
    *(f32x2*)&h[ix] = (f32x2){hv0, hv1};
    const int tg = ch * CL + t;
    if (tg < LSEQ - 1)
      *(f16x2*)&Aparam[(((size_t)(b * LSEQ + tg + 1)) << 12) + DI + d] =
          (f16x2){(f16)hv0, (f16)hv1};
  }
}

// ------------------------- final RMS norm (f32 in, f16 out) -------------------------
__global__ __launch_bounds__(256) void rms_norm(
    const float* __restrict__ uraw, const float* __restrict__ gn,
    f16* __restrict__ u)
{
  const int row = blockIdx.x;
  const size_t base = (size_t)row << 11;
  const int tid = threadIdx.x;
  float uv[8];
  float ss = 0.f;
#pragma unroll
  for (int k = 0; k < 8; ++k) {
    const int c = tid + (k << 8);
    uv[k] = uraw[base + c];
    ss += uv[k] * uv[k];
  }
#pragma unroll
  for (int off = 32; off; off >>= 1) ss += __shfl_xor(ss, off);
  __shared__ float sred[4];
  const int l = tid & 63, w = tid >> 6;
  if (l == 0) sred[w] = ss;
  __syncthreads();
  ss = sred[0] + sred[1] + sred[2] + sred[3];
  const float scale = 1.0f / sqrtf(ss * (1.0f / DI) + EPSF);
#pragma unroll
  for (int k = 0; k < 8; ++k) {
    const int c = tid + (k << 8);
    u[base + c] = (f16)(uv[k] * scale * gn[c]);
  }
}

// ------------------------- launch -------------------------
extern "C" void kernel_launch(void* const* d_in, const int* in_sizes, int n_in,
                              void* d_out, int out_size, void* d_ws, size_t ws_size,
                              hipStream_t stream)
{
  (void)in_sizes; (void)n_in; (void)out_size; (void)d_ws; (void)ws_size;
  const float* x      = (const float*)d_in[0];
  const float* W_in   = (const float*)d_in[1];
  const float* W_b    = (const float*)d_in[2];
  const float* W_lam  = (const float*)d_in[3];
  const float* b_lam  = (const float*)d_in[4];
  const float* W_v    = (const float*)d_in[5];
  const float* b_v    = (const float*)d_in[6];
  const float* W_c    = (const float*)d_in[7];
  const float* g_norm = (const float*)d_in[8];
  const float* W_out  = (const float*)d_in[9];
  float* out = (float*)d_out;

  char* buf = nullptr;
  hipGetSymbolAddress((void**)&buf, HIP_SYMBOL(g_buf));

  f16* Aparam = (f16*)(buf + OFF_APARAM);
  f16* Wvt    = (f16*)(buf + OFF_WVT);
  f16* Wct    = (f16*)(buf + OFF_WCT);
  f16* Wbt    = (f16*)(buf + OFF_WBT);
  f16* Wlt    = (f16*)(buf + OFF_WLT);
  f16* Wint   = (f16*)(buf + OFF_WINT);
  f16* Wot    = (f16*)(buf + OFF_WOT);
  f16* Ax     = (f16*)(buf + OFF_AX);
  f16* Zb     = (f16*)(buf + OFF_Z);
  f16* Ub     = (f16*)(buf + OFF_U);
  float* xi   = (float*)(buf + OFF_XI);
  f16* bxh    = (f16*)(buf + OFF_BXH);
  f16* lamh   = (f16*)(buf + OFF_LAMH);
  float* h    = (float*)(buf + OFF_H);
  float* vraw = (float*)(buf + OFF_VRAW);
  float* vx   = (float*)(buf + OFF_VX);
  float* ssp  = (float*)(buf + OFF_SSP);
  float* drp  = (float*)(buf + OFF_DRP);
  float* cA   = (float*)(buf + OFF_CA);
  float* cB   = (float*)(buf + OFF_CB);

  const dim3 b256(256);
  const dim3 b512(512);
  const dim3 tb(32, 8);

  fill_init<<<dim3(MROWS * DI / 256), b256, 0, stream>>>(h, Aparam);

  // weight transposes (f32 -> f16)
  transpose_f32_f16<<<dim3(128, 32), tb, 0, stream>>>(W_in,  Wint, 1024, 4096);
  transpose_f32_f16<<<dim3(64, 64), tb, 0, stream>>>(W_b,   Wbt,  2048, 2048);
  transpose_f32_f16<<<dim3(64, 64), tb, 0, stream>>>(W_lam, Wlt,  2048, 2048);
  transpose_f32_f16<<<dim3(64, 128), tb, 0, stream>>>(W_v,  Wvt,  4096, 2048);
  transpose_f32_f16<<<dim3(64, 128), tb, 0, stream>>>(W_c,  Wct,  4096, 2048);
  transpose_f32_f16<<<dim3(32, 64), tb, 0, stream>>>(W_out, Wot,  2048, 1024);
  cast_f32_f16<<<dim3(MROWS * 1024 / 256), b256, 0, stream>>>(x, Ax, MROWS * 1024);

  // xz = x @ W_in -> xi(f32) + Aparam(f16), z(f16)
  gemm_f16<1><<<dim3(32 * 32), b512, 0, stream>>>(Ax, 1024, Wint, 1024, 4096, 1024,
      xi, Aparam, Zb, nullptr, nullptr, nullptr, nullptr, nullptr, nullptr);
  // fused pair: bxh = f16(silu(x_i@W_b)*x_i); lamh = f16(sigm(x_i@W_lam+b_lam))
  gemm_f16<8><<<dim3(32 * 32), b512, 0, stream>>>(Aparam, 4096, Wbt, 2048, 4096, 2048,
      nullptr, bxh, lamh, xi, b_lam, nullptr, nullptr, nullptr, nullptr);
  // vx = x_i @ W_v[:DI] + b_v   (f32, loop-invariant)
  gemm_f16<6><<<dim3(32 * 16), b512, 0, stream>>>(Aparam, 4096, Wvt, 4096, 2048, 2048,
      vx, nullptr, nullptr, nullptr, b_v, nullptr, nullptr, nullptr, nullptr);

  for (int s = 0; s < NSTEPS; ++s) {
    // v_raw = silu(h_sh @ W_v[DI:] + vx); fused ss/dr partials vs (bxh, h)
    gemm_f16<4><<<dim3(32 * 16), b512, 0, stream>>>(Aparam + DI, 4096, Wvt + DI, 4096, 2048, 2048,
        vraw, nullptr, nullptr, h, nullptr, vx, bxh, ssp, drp);
    scan_k1<<<dim3(NBATCH * NCH * 4), b256, 0, stream>>>(vraw, bxh, lamh, ssp, drp, cA, cB);
    scan_k2<<<dim3(NBATCH * NCH * 4), b256, 0, stream>>>(vraw, bxh, lamh, ssp, drp, cA, cB, h, Aparam);
  }

  // u_raw = silu([x_i|h_sh] @ W_c) * h * silu(z)   (f32, reuses vraw)
  gemm_f16<5><<<dim3(32 * 16), b512, 0, stream>>>(Aparam, 4096, Wct, 4096, 2048, 4096,
      vraw, nullptr, nullptr, h, nullptr, nullptr, Zb, nullptr, nullptr);
  rms_norm<<<dim3(MROWS), b256, 0, stream>>>(vraw, g_norm, Ub);
  // out = u @ W_out
  gemm_f16<0><<<dim3(32 * 8), b512, 0, stream>>>(Ub, 2048, Wot, 2048, 1024, 2048,
      out, nullptr, nullptr, nullptr, nullptr, nullptr, nullptr, nullptr, nullptr);
}

// Round 15
// 3241.087 us; speedup vs baseline: 1.0925x; 1.0352x over previous
//
#include <hip/hip_runtime.h>
#include <hip/hip_bf16.h>
#include <hip/hip_fp16.h>

#define DI     2048
#define LSEQ   2048
#define NBATCH 2
#define MROWS  4096        // NBATCH * LSEQ
#define EPSF   1e-5f
#define NSTEPS 31
#define NCH    64          // scan chunks per sequence
#define CL     32          // chunk length (NCH*CL == LSEQ)

typedef float    f32x4 __attribute__((ext_vector_type(4)));
typedef float    f32x2 __attribute__((ext_vector_type(2)));
typedef _Float16 f16x8 __attribute__((ext_vector_type(8)));
typedef _Float16 f16x2 __attribute__((ext_vector_type(2)));
using f16 = _Float16;

// ------------------------- static device arena -------------------------
constexpr size_t MB = 1024ull * 1024ull;
constexpr size_t OFF_APARAM =   0 * MB;   // f16 [4096][4096] = [x_i | h_sh]   (32 MB)
constexpr size_t OFF_WVT    =  32 * MB;   // f16 [2048][4096] W_v^T            (16 MB)
constexpr size_t OFF_WCT    =  48 * MB;   // f16 [2048][4096] W_c^T            (16 MB)
constexpr size_t OFF_WBT    =  64 * MB;   // f16 [2048][2048] W_b^T            ( 8 MB)  (contiguous
constexpr size_t OFF_WLT    =  72 * MB;   // f16 [2048][2048] W_lam^T          ( 8 MB)   with WBT)
constexpr size_t OFF_WINT   =  80 * MB;   // f16 [4096][1024] W_in^T           ( 8 MB)
constexpr size_t OFF_WOT    =  88 * MB;   // f16 [1024][2048] W_out^T          ( 4 MB)
constexpr size_t OFF_AX     =  92 * MB;   // f16 [4096][1024] x                ( 8 MB)
constexpr size_t OFF_Z      = 100 * MB;   // f16 [4096][2048] z                (16 MB)
constexpr size_t OFF_U      = 116 * MB;   // f16 [4096][2048] u (normed)       (16 MB)
constexpr size_t OFF_XI     = 132 * MB;   // f32 [4096][2048] x_i              (32 MB)
constexpr size_t OFF_BXH    = 164 * MB;   // f16 b*x_i        (step-invariant) (16 MB)
constexpr size_t OFF_LAMH   = 180 * MB;   // f16 lam          (step-invariant) (16 MB)
constexpr size_t OFF_H      = 196 * MB;   // f32 h (step-varying: stays f32)   (32 MB)
constexpr size_t OFF_VRAW   = 228 * MB;   // f32 v_raw / u_raw                 (32 MB)
constexpr size_t OFF_VX     = 260 * MB;   // f32 x_i@Wv_top + b_v              (32 MB)
constexpr size_t OFF_SSP    = 292 * MB;   // f32 [4096][64] ss partials        ( 1 MB)
constexpr size_t OFF_DRP    = 293 * MB;   // f32 [4096][64] dr partials        ( 1 MB)
constexpr size_t OFF_CA     = 294 * MB;   // f32 [2][64][2048]                 ( 1 MB)
constexpr size_t OFF_CB     = 295 * MB;   //                                   ( 1 MB)
constexpr size_t ARENA_SZ   = 296 * MB;

__device__ __align__(256) char g_buf[ARENA_SZ];

// ------------------------- helpers -------------------------
__device__ __forceinline__ void gload16(const void* g, void* l) {
  __builtin_amdgcn_global_load_lds((const __attribute__((address_space(1))) void*)g,
                                   (__attribute__((address_space(3))) void*)l, 16, 0, 0);
}
__device__ __forceinline__ float siluf(float x) { return x / (1.0f + __expf(-x)); }
__device__ __forceinline__ float sigmf(float x) { return 1.0f / (1.0f + __expf(-x)); }

// ------------------------- GEMM: C = A(f16,MxK) * Bt(f16,NxK)^T -------------------------
// 128x128 tile, BK=64, 8 waves (512 thr), 64x32 per wave, dbuf LDS, counted vmcnt(4),
// XCD swizzle.  ROUND-11/14 VERIFIED OPTIMUM — do not perturb without bisect discipline.
// Banned by bisect evidence: mixed-NW instantiations (r7/8 NaN), cooperative launches
// (r10 graph-capture abort), BK=32 (r12: grid-limited, −5%), extra per-step launches
// (r13 sc_pre: +5 µs/step launch gap).
// EPI 0: outf[row*N+col] = acc
// EPI 1: split xz: col<DI -> xi(f32)+Aparam(f16); else z(f16)
// EPI 4: v = silu(acc + aux2(vx)); outf(vraw)=v; ss/dr partials (auxb=bxh f16, aux0=h f32)
// EPI 5: outf(uraw) = silu(acc) * aux0(h) * silu(auxb(z))
// EPI 6: outf(vx) = acc + aux1[col](b_v)
// EPI 8: fused pair (N=4096): col<DI -> bxh = f16(silu(acc)*aux0(xi));
//        else lamh = f16(sigm(acc + aux1[col-DI](b_lam)))
template<int EPI>
__global__ __launch_bounds__(512) void gemm_f16(
    const f16* __restrict__ A, int lda,
    const f16* __restrict__ Bt, int ldb,
    int N, int K,
    float* __restrict__ outf,
    f16* __restrict__ outb,
    f16* __restrict__ outb2,
    const float* __restrict__ aux0,
    const float* __restrict__ aux1,
    const float* __restrict__ aux2,
    const f16* __restrict__ auxb,
    float* __restrict__ ssp,
    float* __restrict__ drp)
{
  __shared__ char As[2][128 * 64 * 2];   // 16 KB per buffer
  __shared__ char Bs[2][128 * 64 * 2];

  const int tid = threadIdx.x;
  const int l   = tid & 63;
  const int w   = tid >> 6;              // 0..7
  const int wm  = (w >> 2) << 6;         // 0 or 64   (64-row wave tile)
  const int wn  = (w & 3) << 5;          // 0/32/64/96 (32-col wave tile)
  const int ntn = N >> 7;
  // XCD-aware swizzle (grid % 8 == 0 for all our shapes)
  const int nwg = (int)gridDim.x;
  const int id  = (blockIdx.x & 7) * (nwg >> 3) + (blockIdx.x >> 3);
  const int bm  = id / ntn;
  const int bn  = id % ntn;
  const size_t m0 = (size_t)bm << 7;
  const size_t n0 = (size_t)bn << 7;

  const char* Ab = (const char*)A + m0 * (size_t)(lda * 2);
  const char* Bb = (const char*)Bt + n0 * (size_t)(ldb * 2);

  f32x4 acc[4][2];
#pragma unroll
  for (int i = 0; i < 4; ++i)
#pragma unroll
    for (int j = 0; j < 2; ++j) acc[i][j] = (f32x4){0.f, 0.f, 0.f, 0.f};

  auto stage = [&](int bf, int kte) {   // kte = element offset in K; 4 loads/thread
#pragma unroll
    for (int rep = 0; rep < 2; ++rep) {
      const int o   = tid + (rep << 9);      // 16B-chunk 0..1023
      const int r   = o >> 3;                // tile row
      const int cb  = (o & 7) << 4;          // byte col in 128B row
      const int scb = cb ^ ((r & 7) << 4);   // pre-swizzled source col
      gload16(Ab + (size_t)r * (size_t)(lda * 2) + (size_t)kte * 2 + scb, &As[bf][o << 4]);
      gload16(Bb + (size_t)r * (size_t)(ldb * 2) + (size_t)kte * 2 + scb, &Bs[bf][o << 4]);
    }
  };

  const int nt = K >> 6;
  stage(0, 0);                               // prologue: tile 0 in flight (4 loads/thread)
  for (int t = 0; t < nt; ++t) {
    const int cur = t & 1;
    if (t + 1 < nt) {
      stage(cur ^ 1, (t + 1) << 6);          // prefetch next tile (4 more in flight)
      asm volatile("s_waitcnt vmcnt(4)" ::: "memory");   // wait only for tile t
    } else {
      asm volatile("s_waitcnt vmcnt(0)" ::: "memory");
    }
    __builtin_amdgcn_s_barrier();
    __builtin_amdgcn_sched_barrier(0);
    const char* Asc = As[cur];
    const char* Bsc = Bs[cur];
#pragma unroll
    for (int kk = 0; kk < 2; ++kk) {
      f16x8 af[4], bfr[2];
      const int kb = (kk << 6) + ((l >> 4) << 4);
#pragma unroll
      for (int i = 0; i < 4; ++i) {
        const int Ra = wm + (i << 4) + (l & 15);
        af[i] = *(const f16x8*)(Asc + (Ra << 7) + (kb ^ ((Ra & 7) << 4)));
      }
#pragma unroll
      for (int j = 0; j < 2; ++j) {
        const int Rb = wn + (j << 4) + (l & 15);
        bfr[j] = *(const f16x8*)(Bsc + (Rb << 7) + (kb ^ ((Rb & 7) << 4)));
      }
#pragma unroll
      for (int i = 0; i < 4; ++i)
#pragma unroll
        for (int j = 0; j < 2; ++j)
          acc[i][j] = __builtin_amdgcn_mfma_f32_16x16x32_f16(af[i], bfr[j], acc[i][j], 0, 0, 0);
    }
    __builtin_amdgcn_sched_barrier(0);
    __builtin_amdgcn_s_barrier();
    __builtin_amdgcn_sched_barrier(0);
  }

  // epilogue: C/D layout col=lane&15, row=(lane>>4)*4+reg
  if constexpr (EPI == 4) {
#pragma unroll
    for (int i = 0; i < 4; ++i) {
#pragma unroll
      for (int rg = 0; rg < 4; ++rg) {
        const size_t row = m0 + wm + (i << 4) + ((l >> 4) << 2) + rg;
        float ssl = 0.f, drl = 0.f;
#pragma unroll
        for (int j = 0; j < 2; ++j) {
          const size_t col = n0 + wn + (j << 4) + (l & 15);
          const size_t idx = (row << 11) + col;
          const float v = siluf(acc[i][j][rg] + aux2[idx]);
          outf[idx] = v;
          ssl += v * v;
          drl += ((float)auxb[idx] - aux0[idx]) * v;   // (bx - h_prev) * v
        }
#pragma unroll
        for (int m = 8; m; m >>= 1) {           // reduce within 16-lane col group
          ssl += __shfl_xor(ssl, m);
          drl += __shfl_xor(drl, m);
        }
        if ((l & 15) == 0) {
          const int nb = (int)((n0 + wn) >> 5);  // 0..63 (32-col slots)
          ssp[(row << 6) + nb] = ssl;
          drp[(row << 6) + nb] = drl;
        }
      }
    }
  } else {
#pragma unroll
    for (int i = 0; i < 4; ++i) {
#pragma unroll
      for (int j = 0; j < 2; ++j) {
#pragma unroll
        for (int rg = 0; rg < 4; ++rg) {
          const size_t row = m0 + wm + (i << 4) + ((l >> 4) << 2) + rg;
          const size_t col = n0 + wn + (j << 4) + (l & 15);
          const float v = acc[i][j][rg];
          if constexpr (EPI == 0) {
            outf[row * (size_t)N + col] = v;
          } else if constexpr (EPI == 1) {
            if (col < DI) {
              outf[(row << 11) + col] = v;
              outb[(row << 12) + col] = (f16)v;
            } else {
              outb2[(row << 11) + (col - DI)] = (f16)v;
            }
          } else if constexpr (EPI == 5) {
            const size_t idx = (row << 11) + col;
            outf[idx] = siluf(v) * aux0[idx] * siluf((float)auxb[idx]);
          } else if constexpr (EPI == 6) {
            const size_t idx = (row << 11) + col;
            outf[idx] = v + aux1[col];
          } else if constexpr (EPI == 8) {
            if (col < DI) {
              const size_t idx = (row << 11) + col;
              outb[idx] = (f16)(siluf(v) * aux0[idx]);          // bxh
            } else {
              const size_t idx = (row << 11) + (col - DI);
              outb2[idx] = (f16)sigmf(v + aux1[col - DI]);      // lamh
            }
          }
        }
      }
    }
  }
}

// ------------------------- prep kernels -------------------------
__global__ __launch_bounds__(256) void transpose_f32_f16(
    const float* __restrict__ in, f16* __restrict__ out, int R, int C)
{
  __shared__ float t[32][33];
  const int bx = blockIdx.x * 32;
  const int by = blockIdx.y * 32;
  const int lx = threadIdx.x;
  const int ly = threadIdx.y;
#pragma unroll
  for (int i = 0; i < 32; i += 8)
    t[ly + i][lx] = in[(size_t)(by + ly + i) * C + bx + lx];
  __syncthreads();
#pragma unroll
  for (int i = 0; i < 32; i += 8)
    out[(size_t)(bx + ly + i) * R + by + lx] = (f16)t[lx][ly + i];
}

__global__ __launch_bounds__(256) void cast_f32_f16(
    const float* __restrict__ in, f16* __restrict__ out, int n)
{
  const int i = blockIdx.x * 256 + threadIdx.x;
  if (i < n) out[i] = (f16)in[i];
}

__global__ __launch_bounds__(256) void fill_init(
    float* __restrict__ h, f16* __restrict__ Aparam)
{
  const int idx = blockIdx.x * 256 + threadIdx.x;   // 0 .. 4096*2048-1
  h[idx] = 0.0f;
  const int r = idx >> 11, c = idx & 2047;
  Aparam[((size_t)r << 12) + DI + c] = (f16)0.0f;
}

// ------------------------- scan, stage 1: sc + chunk summaries (no inp write) ----------
// block = (b, ch, g): g in [0,4), 256 threads x 2 channels (float2).
// x_tilde = bx - sc*v  (h_prev cancels); inp = (1-lam)*x_tilde  (recomputed in k2).
__global__ __launch_bounds__(256) void scan_k1(
    const float* __restrict__ vraw, const f16* __restrict__ bxh,
    const f16* __restrict__ lamh,
    const float* __restrict__ ssp, const float* __restrict__ drp,
    float* __restrict__ cA, float* __restrict__ cB)
{
  const int bid = blockIdx.x;
  const int g  = bid & 3;
  const int ch = (bid >> 2) & (NCH - 1);
  const int b  = bid >> 8;
  const int tid = threadIdx.x;
  const int d = (g << 9) + (tid << 1);

  __shared__ float sc_s[CL];
  if (tid < CL) {
    const int grow = b * LSEQ + ch * CL + tid;
    float ss = 0.f, dr = 0.f;
    const f32x4* sp = (const f32x4*)&ssp[(size_t)grow << 6];
    const f32x4* dp = (const f32x4*)&drp[(size_t)grow << 6];
#pragma unroll
    for (int p = 0; p < 16; ++p) {
      const f32x4 s4 = sp[p], d4 = dp[p];
      ss += s4.x + s4.y + s4.z + s4.w;
      dr += d4.x + d4.y + d4.z + d4.w;
    }
    const float n = sqrtf(ss) + EPSF;
    sc_s[tid] = 2.0f * dr / (n * n);
  }
  __syncthreads();

  const size_t base = ((size_t)(b * LSEQ + ch * CL) << 11) + d;
  float hv0 = 0.f, hv1 = 0.f, A0 = 1.f, A1 = 1.f;
#pragma unroll 4
  for (int t = 0; t < CL; ++t) {
    const size_t ix = base + ((size_t)t << 11);
    const f16x2 la2 = *(const f16x2*)&lamh[ix];
    const f16x2 bb2 = *(const f16x2*)&bxh[ix];
    const f32x2 v   = *(const f32x2*)&vraw[ix];
    const float lax = (float)la2.x, lay = (float)la2.y;
    const float sc  = sc_s[t];
    const float i0 = (1.0f - lax) * ((float)bb2.x - sc * v.x);
    const float i1 = (1.0f - lay) * ((float)bb2.y - sc * v.y);
    hv0 = lax * hv0 + i0;
    hv1 = lay * hv1 + i1;
    A0 *= lax;
    A1 *= lay;
  }
  const size_t ci = ((size_t)(b * NCH + ch) << 11) + d;
  *(f32x2*)&cA[ci] = (f32x2){A0, A1};
  *(f32x2*)&cB[ci] = (f32x2){hv0, hv1};
}

// ------------------------- scan, stage 2: carry + recompute inp + write h/Aparam -------
// sc_s recomputation is bit-identical to k1 (same inputs, same op order).
// Carry loop: 4x-batched INDEPENDENT loads + IN-ORDER FMA chain (bit-identical to the
// rolled loop; hides the ~200cyc L2 latency 4-deep -> tail block carry ~5us -> ~1.3us).
__global__ __launch_bounds__(256) void scan_k2(
    const float* __restrict__ vraw, const f16* __restrict__ bxh,
    const f16* __restrict__ lamh,
    const float* __restrict__ ssp, const float* __restrict__ drp,
    const float* __restrict__ cA, const float* __restrict__ cB,
    float* __restrict__ h, f16* __restrict__ Aparam)
{
  const int bid = blockIdx.x;
  const int g  = bid & 3;
  const int ch = (bid >> 2) & (NCH - 1);
  const int b  = bid >> 8;
  const int tid = threadIdx.x;
  const int d = (g << 9) + (tid << 1);

  __shared__ float sc_s[CL];
  if (tid < CL) {
    const int grow = b * LSEQ + ch * CL + tid;
    float ss = 0.f, dr = 0.f;
    const f32x4* sp = (const f32x4*)&ssp[(size_t)grow << 6];
    const f32x4* dp = (const f32x4*)&drp[(size_t)grow << 6];
#pragma unroll
    for (int p = 0; p < 16; ++p) {
      const f32x4 s4 = sp[p], d4 = dp[p];
      ss += s4.x + s4.y + s4.z + s4.w;
      dr += d4.x + d4.y + d4.z + d4.w;
    }
    const float n = sqrtf(ss) + EPSF;
    sc_s[tid] = 2.0f * dr / (n * n);
  }
  __syncthreads();

  float hv0 = 0.f, hv1 = 0.f;
  {
    int cc = 0;
    for (; cc + 4 <= ch; cc += 4) {
      // 8 independent loads issued together, then FMAs applied in original order
      f32x2 a0, a1_, a2_, a3_, b0, b1_, b2_, b3_;
      {
        const size_t c0 = ((size_t)(b * NCH + cc    ) << 11) + d;
        const size_t c1 = ((size_t)(b * NCH + cc + 1) << 11) + d;
        const size_t c2 = ((size_t)(b * NCH + cc + 2) << 11) + d;
        const size_t c3 = ((size_t)(b * NCH + cc + 3) << 11) + d;
        a0  = *(const f32x2*)&cA[c0]; b0  = *(const f32x2*)&cB[c0];
        a1_ = *(const f32x2*)&cA[c1]; b1_ = *(const f32x2*)&cB[c1];
        a2_ = *(const f32x2*)&cA[c2]; b2_ = *(const f32x2*)&cB[c2];
        a3_ = *(const f32x2*)&cA[c3]; b3_ = *(const f32x2*)&cB[c3];
      }
      hv0 = a0.x  * hv0 + b0.x;   hv1 = a0.y  * hv1 + b0.y;
      hv0 = a1_.x * hv0 + b1_.x;  hv1 = a1_.y * hv1 + b1_.y;
      hv0 = a2_.x * hv0 + b2_.x;  hv1 = a2_.y * hv1 + b2_.y;
      hv0 = a3_.x * hv0 + b3_.x;  hv1 = a3_.y * hv1 + b3_.y;
    }
    for (; cc < ch; ++cc) {
      const size_t ci = ((size_t)(b * NCH + cc) << 11) + d;
      const f32x2 a  = *(const f32x2*)&cA[ci];
      const f32x2 bb = *(const f32x2*)&cB[ci];
      hv0 = a.x * hv0 + bb.x;
      hv1 = a.y * hv1 + bb.y;
    }
  }

  const size_t base = ((size_t)(b * LSEQ + ch * CL) << 11) + d;
#pragma unroll 4
  for (int t = 0; t < CL; ++t) {
    const size_t ix = base + ((size_t)t << 11);
    const f16x2 la2 = *(const f16x2*)&lamh[ix];
    const f16x2 bb2 = *(const f16x2*)&bxh[ix];
    const f32x2 v   = *(const f32x2*)&vraw[ix];
    const float lax = (float)la2.x, lay = (float)la2.y;
    const float sc  = sc_s[t];
    const float i0 = (1.0f - lax) * ((float)bb2.x - sc * v.x);
    const float i1 = (1.0f - lay) * ((float)bb2.y - sc * v.y);
    hv0 = lax * hv0 + i0;
    hv1 = lay * hv1 + i1;
    *(f32x2*)&h[ix] = (f32x2){hv0, hv1};
    const int tg = ch * CL + t;
    if (tg < LSEQ - 1)
      *(f16x2*)&Aparam[(((size_t)(b * LSEQ + tg + 1)) << 12) + DI + d] =
          (f16x2){(f16)hv0, (f16)hv1};
  }
}

// ------------------------- final RMS norm (f32 in, f16 out) -------------------------
__global__ __launch_bounds__(256) void rms_norm(
    const float* __restrict__ uraw, const float* __restrict__ gn,
    f16* __restrict__ u)
{
  const int row = blockIdx.x;
  const size_t base = (size_t)row << 11;
  const int tid = threadIdx.x;
  float uv[8];
  float ss = 0.f;
#pragma unroll
  for (int k = 0; k < 8; ++k) {
    const int c = tid + (k << 8);
    uv[k] = uraw[base + c];
    ss += uv[k] * uv[k];
  }
#pragma unroll
  for (int off = 32; off; off >>= 1) ss += __shfl_xor(ss, off);
  __shared__ float sred[4];
  const int l = tid & 63, w = tid >> 6;
  if (l == 0) sred[w] = ss;
  __syncthreads();
  ss = sred[0] + sred[1] + sred[2] + sred[3];
  const float scale = 1.0f / sqrtf(ss * (1.0f / DI) + EPSF);
#pragma unroll
  for (int k = 0; k < 8; ++k) {
    const int c = tid + (k << 8);
    u[base + c] = (f16)(uv[k] * scale * gn[c]);
  }
}

// ------------------------- launch -------------------------
extern "C" void kernel_launch(void* const* d_in, const int* in_sizes, int n_in,
                              void* d_out, int out_size, void* d_ws, size_t ws_size,
                              hipStream_t stream)
{
  (void)in_sizes; (void)n_in; (void)out_size; (void)d_ws; (void)ws_size;
  const float* x      = (const float*)d_in[0];
  const float* W_in   = (const float*)d_in[1];
  const float* W_b    = (const float*)d_in[2];
  const float* W_lam  = (const float*)d_in[3];
  const float* b_lam  = (const float*)d_in[4];
  const float* W_v    = (const float*)d_in[5];
  const float* b_v    = (const float*)d_in[6];
  const float* W_c    = (const float*)d_in[7];
  const float* g_norm = (const float*)d_in[8];
  const float* W_out  = (const float*)d_in[9];
  float* out = (float*)d_out;

  char* buf = nullptr;
  hipGetSymbolAddress((void**)&buf, HIP_SYMBOL(g_buf));

  f16* Aparam = (f16*)(buf + OFF_APARAM);
  f16* Wvt    = (f16*)(buf + OFF_WVT);
  f16* Wct    = (f16*)(buf + OFF_WCT);
  f16* Wbt    = (f16*)(buf + OFF_WBT);
  f16* Wlt    = (f16*)(buf + OFF_WLT);
  f16* Wint   = (f16*)(buf + OFF_WINT);
  f16* Wot    = (f16*)(buf + OFF_WOT);
  f16* Ax     = (f16*)(buf + OFF_AX);
  f16* Zb     = (f16*)(buf + OFF_Z);
  f16* Ub     = (f16*)(buf + OFF_U);
  float* xi   = (float*)(buf + OFF_XI);
  f16* bxh    = (f16*)(buf + OFF_BXH);
  f16* lamh   = (f16*)(buf + OFF_LAMH);
  float* h    = (float*)(buf + OFF_H);
  float* vraw = (float*)(buf + OFF_VRAW);
  float* vx   = (float*)(buf + OFF_VX);
  float* ssp  = (float*)(buf + OFF_SSP);
  float* drp  = (float*)(buf + OFF_DRP);
  float* cA   = (float*)(buf + OFF_CA);
  float* cB   = (float*)(buf + OFF_CB);

  const dim3 b256(256);
  const dim3 b512(512);
  const dim3 tb(32, 8);

  fill_init<<<dim3(MROWS * DI / 256), b256, 0, stream>>>(h, Aparam);

  // weight transposes (f32 -> f16)
  transpose_f32_f16<<<dim3(128, 32), tb, 0, stream>>>(W_in,  Wint, 1024, 4096);
  transpose_f32_f16<<<dim3(64, 64), tb, 0, stream>>>(W_b,   Wbt,  2048, 2048);
  transpose_f32_f16<<<dim3(64, 64), tb, 0, stream>>>(W_lam, Wlt,  2048, 2048);
  transpose_f32_f16<<<dim3(64, 128), tb, 0, stream>>>(W_v,  Wvt,  4096, 2048);
  transpose_f32_f16<<<dim3(64, 128), tb, 0, stream>>>(W_c,  Wct,  4096, 2048);
  transpose_f32_f16<<<dim3(32, 64), tb, 0, stream>>>(W_out, Wot,  2048, 1024);
  cast_f32_f16<<<dim3(MROWS * 1024 / 256), b256, 0, stream>>>(x, Ax, MROWS * 1024);

  // xz = x @ W_in -> xi(f32) + Aparam(f16), z(f16)
  gemm_f16<1><<<dim3(32 * 32), b512, 0, stream>>>(Ax, 1024, Wint, 1024, 4096, 1024,
      xi, Aparam, Zb, nullptr, nullptr, nullptr, nullptr, nullptr, nullptr);
  // fused pair: bxh = f16(silu(x_i@W_b)*x_i); lamh = f16(sigm(x_i@W_lam+b_lam))
  gemm_f16<8><<<dim3(32 * 32), b512, 0, stream>>>(Aparam, 4096, Wbt, 2048, 4096, 2048,
      nullptr, bxh, lamh, xi, b_lam, nullptr, nullptr, nullptr, nullptr);
  // vx = x_i @ W_v[:DI] + b_v   (f32, loop-invariant)
  gemm_f16<6><<<dim3(32 * 16), b512, 0, stream>>>(Aparam, 4096, Wvt, 4096, 2048, 2048,
      vx, nullptr, nullptr, nullptr, b_v, nullptr, nullptr, nullptr, nullptr);

  for (int s = 0; s < NSTEPS; ++s) {
    // v_raw = silu(h_sh @ W_v[DI:] + vx); fused ss/dr partials vs (bxh, h)
    gemm_f16<4><<<dim3(32 * 16), b512, 0, stream>>>(Aparam + DI, 4096, Wvt + DI, 4096, 2048, 2048,
        vraw, nullptr, nullptr, h, nullptr, vx, bxh, ssp, drp);
    scan_k1<<<dim3(NBATCH * NCH * 4), b256, 0, stream>>>(vraw, bxh, lamh, ssp, drp, cA, cB);
    scan_k2<<<dim3(NBATCH * NCH * 4), b256, 0, stream>>>(vraw, bxh, lamh, ssp, drp, cA, cB, h, Aparam);
  }

  // u_raw = silu([x_i|h_sh] @ W_c) * h * silu(z)   (f32, reuses vraw)
  gemm_f16<5><<<dim3(32 * 16), b512, 0, stream>>>(Aparam, 4096, Wct, 4096, 2048, 4096,
      vraw, nullptr, nullptr, h, nullptr, nullptr, Zb, nullptr, nullptr);
  rms_norm<<<dim3(MROWS), b256, 0, stream>>>(vraw, g_norm, Ub);
  // out = u @ W_out
  gemm_f16<0><<<dim3(32 * 8), b512, 0, stream>>>(Ub, 2048, Wot, 2048, 1024, 2048,
      out, nullptr, nullptr, nullptr, nullptr, nullptr, nullptr, nullptr, nullptr);
}